// Round 8
// baseline (1062.983 us; speedup 1.0000x reference)
//
#include <hip/hip_runtime.h>
#include <hip/hip_bf16.h>

// ---------------------------------------------------------------------------
// GAT 2-layer, N=16384 nodes, D=512, H=8, E=524288 edges (+self loops)
// GEMMs: split-bf16 3-term MFMA 16x16x32, BM=BN=128, 4 waves x acc[4][4]
// (16 independent chains), slot-major LDS + global_load_lds, single-buffer
// 2-barrier loop, K-split over blockIdx.z (grid always 512 blocks).
// Node kernels: CSR softmax + float4 gather, XCD-pinned. alpha1 fused.
// ---------------------------------------------------------------------------

#define NNODES 16384

typedef unsigned short u16;
typedef unsigned int u32;
typedef __attribute__((ext_vector_type(8))) __bf16 bf16x8;
typedef __attribute__((ext_vector_type(4))) float f32x4;

__device__ __forceinline__ u16 f2bf(float v) {
    u32 u = __builtin_bit_cast(u32, v);
    u32 r = (u + 0x7fffu + ((u >> 16) & 1u)) >> 16;
    return (u16)r;
}
__device__ __forceinline__ float bf2f(u16 s) {
    u32 u = ((u32)s) << 16;
    return __builtin_bit_cast(float, u);
}
__device__ __forceinline__ void split2(float v, u16& h, u16& l) {
    h = f2bf(v);
    l = f2bf(v - bf2f(h));
}

// async global->LDS, 16B per lane; LDS dest is wave-uniform base + lane*16
__device__ __forceinline__ void gload_lds16(const u16* g, u16* l) {
    __builtin_amdgcn_global_load_lds(
        (__attribute__((address_space(1))) void*)(void*)(g),
        (__attribute__((address_space(3))) void*)(void*)(l), 16, 0, 0);
}

// ------------------------------ CSR build ---------------------------------
__global__ void zero_k(int* p, int n) {
    int i = blockIdx.x * 256 + threadIdx.x;
    if (i < n) p[i] = 0;
}

__global__ void count_k(const int* __restrict__ dst, int E, int* __restrict__ deg) {
    int i = blockIdx.x * 256 + threadIdx.x;
    if (i < E) atomicAdd(&deg[dst[i]], 1);
}

__global__ __launch_bounds__(1024) void scan_k(const int* __restrict__ deg,
                                               int* __restrict__ indptr,
                                               int* __restrict__ cursor, int n) {
    __shared__ int sums[1024];
    int t = threadIdx.x;
    int base = t * 16;
    int local[16];
    int s = 0;
    #pragma unroll
    for (int i = 0; i < 16; i++) { local[i] = s; s += deg[base + i]; }
    sums[t] = s;
    __syncthreads();
    for (int off = 1; off < 1024; off <<= 1) {
        int v = (t >= off) ? sums[t - off] : 0;
        __syncthreads();
        sums[t] += v;
        __syncthreads();
    }
    int base_sum = (t == 0) ? 0 : sums[t - 1];
    #pragma unroll
    for (int i = 0; i < 16; i++) {
        int v = base_sum + local[i];
        indptr[base + i] = v;
        cursor[base + i] = v;
    }
    if (t == 1023) indptr[n] = base_sum + s;
}

__global__ void scatter_k(const int* __restrict__ src, const int* __restrict__ dst,
                          int E, int* __restrict__ cursor, int* __restrict__ csr) {
    int i = blockIdx.x * 256 + threadIdx.x;
    if (i < E) {
        int pos = atomicAdd(&cursor[dst[i]], 1);
        csr[pos] = src[i];
    }
}

// ------------------------- split-bf16 prep kernels -------------------------
__global__ void prepx_k(const float* __restrict__ x, u16* __restrict__ xh,
                        u16* __restrict__ xl) {
    int idx = blockIdx.x * 256 + threadIdx.x;
    int e = idx << 2;
    int n = e >> 9, k = e & 511;
    int g = n >> 10, s = n & 1023;
    float4 v = *(const float4*)(x + ((size_t)(s * 16 + g) << 9) + k);
    u16 h[4], l[4];
    split2(v.x, h[0], l[0]);
    split2(v.y, h[1], l[1]);
    split2(v.z, h[2], l[2]);
    split2(v.w, h[3], l[3]);
    size_t o = ((size_t)n << 9) + k;
    *(ushort4*)(xh + o) = make_ushort4(h[0], h[1], h[2], h[3]);
    *(ushort4*)(xl + o) = make_ushort4(l[0], l[1], l[2], l[3]);
}

// W0t[n][k] = W0[k][n], tiled 64x64 transpose through LDS (coalesced both ways)
__global__ __launch_bounds__(256) void prepW0t_k(const float* __restrict__ W0,
                                                 u16* __restrict__ Wh,
                                                 u16* __restrict__ Wl) {
    __shared__ u32 tile[64][65];
    int b = blockIdx.x;
    int kt = (b >> 3) * 64, nt = (b & 7) * 64;
    int t = threadIdx.x;
    #pragma unroll
    for (int i = 0; i < 16; i++) {
        int idx = i * 256 + t;
        int r = idx >> 6, c = idx & 63;
        float v = W0[(size_t)(kt + r) * 512 + nt + c];
        u16 h, l;
        split2(v, h, l);
        tile[r][c] = ((u32)h << 16) | l;
    }
    __syncthreads();
    #pragma unroll
    for (int i = 0; i < 8; i++) {
        int idx = i * 256 + t;
        int r = idx >> 5, c2 = (idx & 31) * 2;
        u32 p0 = tile[c2][r], p1 = tile[c2 + 1][r];
        size_t o = (size_t)(nt + r) * 512 + kt + c2;
        *(ushort2*)(Wh + o) = make_ushort2((u16)(p0 >> 16), (u16)(p1 >> 16));
        *(ushort2*)(Wl + o) = make_ushort2((u16)(p0 & 0xffff), (u16)(p1 & 0xffff));
    }
}

// B1t[c][h*512+k] = W1[k][h*512+c]/8, per-head tiled 64x64 transpose
__global__ __launch_bounds__(256) void prepW1t_k(const float* __restrict__ W1,
                                                 u16* __restrict__ Bh,
                                                 u16* __restrict__ Bl) {
    __shared__ u32 tile[64][65];
    int b = blockIdx.x;
    int hh = b >> 6;
    int rem = b & 63;
    int kt = (rem >> 3) * 64, ct = (rem & 7) * 64;
    int t = threadIdx.x;
    #pragma unroll
    for (int i = 0; i < 16; i++) {
        int idx = i * 256 + t;
        int r = idx >> 6, c = idx & 63;
        float v = W1[(size_t)(kt + r) * 4096 + hh * 512 + ct + c] * 0.125f;
        u16 h, l;
        split2(v, h, l);
        tile[r][c] = ((u32)h << 16) | l;
    }
    __syncthreads();
    #pragma unroll
    for (int i = 0; i < 8; i++) {
        int idx = i * 256 + t;
        int r = idx >> 5, c2 = (idx & 31) * 2;
        u32 p0 = tile[c2][r], p1 = tile[c2 + 1][r];
        size_t o = (size_t)(ct + r) * 4096 + hh * 512 + kt + c2;
        *(ushort2*)(Bh + o) = make_ushort2((u16)(p0 >> 16), (u16)(p1 >> 16));
        *(ushort2*)(Bl + o) = make_ushort2((u16)(p0 & 0xffff), (u16)(p1 & 0xffff));
    }
}

// ---------------------------------------------------------------------------
// mgemm4: C[M,512] = A[M,K] @ Bt[512,K]^T, split-bf16 3-term, 16x16x32 MFMA.
// BM=BN=128, BK=32, 4 waves (2x2), each wave 64x64 = acc[4][4] (16 chains).
// Slot-major LDS: 16B chunk (row, slot) at index slot*128 + row. Staging:
// wave w stages plane w (8 segs x 1KB), linear LDS dest per seg.
// Single buffer, 2 barriers per K-tile (round-5-proven loop shape).
// SPLIT=0: direct store to C. SPLIT=1: K split over blockIdx.z into P.
// ---------------------------------------------------------------------------
template <int SPLIT>
__global__ __launch_bounds__(256) void mgemm4_k(
    const u16* __restrict__ Ah, const u16* __restrict__ Al,
    const u16* __restrict__ Bh, const u16* __restrict__ Bl,
    float* __restrict__ C, int K, float* __restrict__ P) {
    __shared__ u16 sm[16384];  // 32 KB: A_h|A_l|B_h|B_l planes of 4096 u16

    int t = threadIdx.x;
    int lane = t & 63, w = t >> 6;
    int wr = w >> 1, wc = w & 1;
    int row0 = blockIdx.y * 128, col0 = blockIdx.x * 128;
    int kcnt = SPLIT ? (K / (int)gridDim.z) : K;
    int kbeg = SPLIT ? ((int)blockIdx.z * kcnt) : 0;

    f32x4 acc[4][4];
    #pragma unroll
    for (int i = 0; i < 4; i++)
        #pragma unroll
        for (int j = 0; j < 4; j++) acc[i][j] = (f32x4){0.f, 0.f, 0.f, 0.f};

    // staging role: one plane per wave (8 KB = 8 segments of 64 lanes x 16B)
    const u16* gb;
    int po, g0;
    if (w == 0) { gb = Ah; po = 0; g0 = row0; }
    else if (w == 1) { gb = Al; po = 4096; g0 = row0; }
    else if (w == 2) { gb = Bh; po = 8192; g0 = col0; }
    else { gb = Bl; po = 12288; g0 = col0; }

    int rl = lane & 15, kb = lane >> 4;

    for (int kk = 0; kk < kcnt; kk += 32) {
        int k0 = kbeg + kk;
        // seg s: rows (s&1)*64+lane, k-slot s>>1 -> chunks (s>>1)*128+(s&1)*64+lane
        #pragma unroll
        for (int s = 0; s < 8; s++) {
            const u16* g = gb + (size_t)(g0 + (s & 1) * 64 + lane) * K + k0 +
                           ((s >> 1) << 3);
            gload_lds16(g, sm + po + (((s >> 1) << 7) + ((s & 1) << 6)) * 8);
        }
        __syncthreads();

        bf16x8 afh[4], afl[4], bfh[4], bfl[4];
        #pragma unroll
        for (int f = 0; f < 4; f++) {
            int offA = ((kb << 7) + wr * 64 + f * 16 + rl) * 8;
            afh[f] = *(const bf16x8*)(sm + offA);
            afl[f] = *(const bf16x8*)(sm + 4096 + offA);
            int offB = ((kb << 7) + wc * 64 + f * 16 + rl) * 8;
            bfh[f] = *(const bf16x8*)(sm + 8192 + offB);
            bfl[f] = *(const bf16x8*)(sm + 12288 + offB);
        }
        #pragma unroll
        for (int i = 0; i < 4; i++)
            #pragma unroll
            for (int j = 0; j < 4; j++) {
                acc[i][j] = __builtin_amdgcn_mfma_f32_16x16x32_bf16(
                    afl[i], bfh[j], acc[i][j], 0, 0, 0);
                acc[i][j] = __builtin_amdgcn_mfma_f32_16x16x32_bf16(
                    afh[i], bfl[j], acc[i][j], 0, 0, 0);
                acc[i][j] = __builtin_amdgcn_mfma_f32_16x16x32_bf16(
                    afh[i], bfh[j], acc[i][j], 0, 0, 0);
            }
        __syncthreads();
    }

    // C/D layout 16x16: col = lane&15, row = (lane>>4)*4 + q  (verified)
    int cr = kb * 4;
    #pragma unroll
    for (int i = 0; i < 4; i++) {
        #pragma unroll
        for (int j = 0; j < 4; j++) {
            int col = col0 + wc * 64 + j * 16 + rl;
            f32x4 v = acc[i][j];
            #pragma unroll
            for (int q = 0; q < 4; q++) {
                int row = row0 + wr * 64 + i * 16 + cr + q;
                if (SPLIT) {
                    size_t M = (size_t)gridDim.y * 128;
                    P[((size_t)blockIdx.z * M + row) * 512 + col] = v[q];
                } else {
                    C[(size_t)row * 512 + col] = v[q];
                }
            }
        }
    }
}

// combine K-split partials: out = ELU(sum_bz P[bz] + bias)
__global__ void combine_k(const float* __restrict__ P,
                          const float* __restrict__ bias,
                          float* __restrict__ out, int CH, int NS) {
    int i = blockIdx.x * 256 + threadIdx.x;
    int total4 = CH * 128;
    if (i >= total4) return;
    int e = i << 2;
    size_t stride = (size_t)CH * 512;
    float4 s = *(const float4*)(P + e);
    for (int bz = 1; bz < NS; bz++) {
        float4 a = *(const float4*)(P + bz * stride + e);
        s.x += a.x; s.y += a.y; s.z += a.z; s.w += a.w;
    }
    float4 bv = *(const float4*)(bias + (e & 511));
    s.x += bv.x; s.y += bv.y; s.z += bv.z; s.w += bv.w;
    s.x = s.x > 0.f ? s.x : __expf(s.x) - 1.f;
    s.y = s.y > 0.f ? s.y : __expf(s.y) - 1.f;
    s.z = s.z > 0.f ? s.z : __expf(s.z) - 1.f;
    s.w = s.w > 0.f ? s.w : __expf(s.w) - 1.f;
    *(float4*)(out + e) = s;
}

// ------------------------------ attention ---------------------------------
__global__ __launch_bounds__(256) void alpha0_k(const float* __restrict__ h0,
                                                const float* __restrict__ att_s,
                                                const float* __restrict__ att_d,
                                                float* __restrict__ as_,
                                                float* __restrict__ ad_) {
    int n = blockIdx.x * 4 + (threadIdx.x >> 6);
    int l = threadIdx.x & 63;
    int h = l >> 3, i = l & 7;
    float ps = 0.f, pd = 0.f;
    #pragma unroll
    for (int c = 0; c < 64; c += 8) {
        float v = h0[(size_t)n * 512 + h * 64 + c + i];
        ps += v * att_s[h * 64 + c + i];
        pd += v * att_d[h * 64 + c + i];
    }
    #pragma unroll
    for (int off = 1; off < 8; off <<= 1) {
        ps += __shfl_xor(ps, off);
        pd += __shfl_xor(pd, off);
    }
    if (i == 0) {
        as_[n * 8 + h] = ps;
        ad_[n * 8 + h] = pd;
    }
}

__global__ __launch_bounds__(256) void prep1_k(const float* __restrict__ W1,
                                               const float* __restrict__ as1,
                                               const float* __restrict__ ad1,
                                               float* __restrict__ ws1,
                                               float* __restrict__ wd1) {
    int k = blockIdx.x;
    int t = threadIdx.x;
    int h = t >> 5, lane = t & 31;
    float ps = 0.f, pd = 0.f;
    for (int c = lane; c < 512; c += 32) {
        float w = W1[(size_t)k * 4096 + h * 512 + c];
        ps += w * as1[h * 512 + c];
        pd += w * ad1[h * 512 + c];
    }
    #pragma unroll
    for (int off = 1; off < 32; off <<= 1) {
        ps += __shfl_xor(ps, off);
        pd += __shfl_xor(pd, off);
    }
    if (lane == 0) {
        ws1[k * 8 + h] = ps;
        wd1[k * 8 + h] = pd;
    }
}

// -------- layer-0 node kernel: softmax + aggregate + ELU + fused alpha1 ----
__global__ __launch_bounds__(256) void node0_k(
    const float* __restrict__ h0, const float* __restrict__ asrc,
    const float* __restrict__ adst, const int* __restrict__ indptr,
    const int* __restrict__ csr, const float* __restrict__ b0,
    const float* __restrict__ ws1, const float* __restrict__ wd1,
    float* __restrict__ hl0, float* __restrict__ as1, float* __restrict__ ad1) {
    int d = (blockIdx.x & 7) * (NNODES / 8) + (blockIdx.x >> 3);
    int t = threadIdx.x;
    __shared__ float red[256];
    __shared__ float m_s[8], rz_s[8];
    __shared__ float al[32 * 8];
    __shared__ int sl[32];
    __shared__ float comb[128 * 4];
    __shared__ float pw[2][16];
    int e0 = indptr[d], ne = indptr[d + 1] - e0;
    int h = t & 7, slice = t >> 3;
    float adh = adst[d * 8 + h];

    float mx = -3.0e38f;
    for (int e = slice; e < ne + 1; e += 32) {
        int s = (e < ne) ? csr[e0 + e] : d;
        float v = asrc[s * 8 + h] + adh;
        v = v > 0.f ? v : 0.2f * v;
        mx = fmaxf(mx, v);
    }
    red[t] = mx;
    __syncthreads();
    #pragma unroll
    for (int off = 128; off >= 8; off >>= 1) {
        if (t < off) red[t] = fmaxf(red[t], red[t + off]);
        __syncthreads();
    }
    if (t < 8) m_s[t] = red[t];
    __syncthreads();

    float mh = m_s[h];
    float zs = 0.f;
    for (int e = slice; e < ne + 1; e += 32) {
        int s = (e < ne) ? csr[e0 + e] : d;
        float v = asrc[s * 8 + h] + adh;
        v = v > 0.f ? v : 0.2f * v;
        zs += __expf(v - mh);
    }
    red[t] = zs;
    __syncthreads();
    #pragma unroll
    for (int off = 128; off >= 8; off >>= 1) {
        if (t < off) red[t] += red[t + off];
        __syncthreads();
    }
    if (t < 8) rz_s[t] = 1.0f / (red[t] + 1e-16f);
    __syncthreads();

    int half = t >> 7, c4 = t & 127;
    int hc = c4 >> 4;
    float4 acc4 = make_float4(0.f, 0.f, 0.f, 0.f);
    for (int eb = 0; eb < ne + 1; eb += 32) {
        int nn = min(32, ne + 1 - eb);
        __syncthreads();
        if (t < nn * 8) {  // t = el*8 + hh
            int el = t >> 3, hh = t & 7;
            int s = (eb + el < ne) ? csr[e0 + eb + el] : d;
            if (hh == 0) sl[el] = s;
            float v = asrc[s * 8 + hh] + adst[d * 8 + hh];
            v = v > 0.f ? v : 0.2f * v;
            al[t] = __expf(v - m_s[hh]) * rz_s[hh];
        }
        __syncthreads();
        for (int el = half; el < nn; el += 2) {
            int s = sl[el];
            float a = al[el * 8 + hc];
            float4 v = *(const float4*)(h0 + ((size_t)s << 9) + 4 * c4);
            acc4.x = fmaf(a, v.x, acc4.x);
            acc4.y = fmaf(a, v.y, acc4.y);
            acc4.z = fmaf(a, v.z, acc4.z);
            acc4.w = fmaf(a, v.w, acc4.w);
        }
    }
    if (half) *(float4*)&comb[c4 * 4] = acc4;
    __syncthreads();
    if (!half) {
        float4 c2 = *(const float4*)&comb[c4 * 4];
        float4 bv = *(const float4*)(b0 + 4 * c4);
        float4 o;
        o.x = acc4.x + c2.x + bv.x;
        o.y = acc4.y + c2.y + bv.y;
        o.z = acc4.z + c2.z + bv.z;
        o.w = acc4.w + c2.w + bv.w;
        o.x = o.x > 0.f ? o.x : __expf(o.x) - 1.f;
        o.y = o.y > 0.f ? o.y : __expf(o.y) - 1.f;
        o.z = o.z > 0.f ? o.z : __expf(o.z) - 1.f;
        o.w = o.w > 0.f ? o.w : __expf(o.w) - 1.f;
        *(float4*)(hl0 + ((size_t)d << 9) + 4 * c4) = o;

        float ps[8] = {}, pd[8] = {};
        float oq[4] = {o.x, o.y, o.z, o.w};
        #pragma unroll
        for (int q = 0; q < 4; q++) {
            const float4* w4 = (const float4*)(ws1 + (size_t)(4 * c4 + q) * 8);
            const float4* v4 = (const float4*)(wd1 + (size_t)(4 * c4 + q) * 8);
            float4 wa = w4[0], wb = w4[1];
            float4 va = v4[0], vb = v4[1];
            ps[0] = fmaf(oq[q], wa.x, ps[0]);
            ps[1] = fmaf(oq[q], wa.y, ps[1]);
            ps[2] = fmaf(oq[q], wa.z, ps[2]);
            ps[3] = fmaf(oq[q], wa.w, ps[3]);
            ps[4] = fmaf(oq[q], wb.x, ps[4]);
            ps[5] = fmaf(oq[q], wb.y, ps[5]);
            ps[6] = fmaf(oq[q], wb.z, ps[6]);
            ps[7] = fmaf(oq[q], wb.w, ps[7]);
            pd[0] = fmaf(oq[q], va.x, pd[0]);
            pd[1] = fmaf(oq[q], va.y, pd[1]);
            pd[2] = fmaf(oq[q], va.z, pd[2]);
            pd[3] = fmaf(oq[q], va.w, pd[3]);
            pd[4] = fmaf(oq[q], vb.x, pd[4]);
            pd[5] = fmaf(oq[q], vb.y, pd[5]);
            pd[6] = fmaf(oq[q], vb.z, pd[6]);
            pd[7] = fmaf(oq[q], vb.w, pd[7]);
        }
        #pragma unroll
        for (int off = 1; off < 64; off <<= 1) {
            #pragma unroll
            for (int hh = 0; hh < 8; hh++) {
                ps[hh] += __shfl_xor(ps[hh], off);
                pd[hh] += __shfl_xor(pd[hh], off);
            }
        }
        if ((t & 63) == 0) {
            int wv = t >> 6;
            #pragma unroll
            for (int hh = 0; hh < 8; hh++) {
                pw[wv][hh] = ps[hh];
                pw[wv][8 + hh] = pd[hh];
            }
        }
    }
    __syncthreads();
    if (t < 8) as1[(size_t)d * 8 + t] = pw[0][t] + pw[1][t];
    else if (t < 16) ad1[(size_t)d * 8 + t - 8] = pw[0][t] + pw[1][t];
}

// -------- layer-1 node kernel: softmax + per-head aggregate -> split bf16 ---
__global__ __launch_bounds__(256) void node1_k(const float* __restrict__ hl0,
                                               const float* __restrict__ asrc,
                                               const float* __restrict__ adst,
                                               const int* __restrict__ indptr,
                                               const int* __restrict__ csr,
                                               u16* __restrict__ aggh,
                                               u16* __restrict__ aggl,
                                               int base, int ch) {
    int dl = (blockIdx.x & 7) * (ch >> 3) + (blockIdx.x >> 3);
    int d = base + dl;
    int t = threadIdx.x;
    __shared__ float red[256];
    __shared__ float m_s[8], rz_s[8];
    __shared__ float al[32 * 8];
    __shared__ int sl[32];
    __shared__ float comb1[8][128 * 4];
    int e0 = indptr[d], ne = indptr[d + 1] - e0;
    int h = t & 7, slice = t >> 3;
    float adh = adst[d * 8 + h];

    float mx = -3.0e38f;
    for (int e = slice; e < ne + 1; e += 32) {
        int s = (e < ne) ? csr[e0 + e] : d;
        float v = asrc[s * 8 + h] + adh;
        v = v > 0.f ? v : 0.2f * v;
        mx = fmaxf(mx, v);
    }
    red[t] = mx;
    __syncthreads();
    #pragma unroll
    for (int off = 128; off >= 8; off >>= 1) {
        if (t < off) red[t] = fmaxf(red[t], red[t + off]);
        __syncthreads();
    }
    if (t < 8) m_s[t] = red[t];
    __syncthreads();

    float mh = m_s[h];
    float zs = 0.f;
    for (int e = slice; e < ne + 1; e += 32) {
        int s = (e < ne) ? csr[e0 + e] : d;
        float v = asrc[s * 8 + h] + adh;
        v = v > 0.f ? v : 0.2f * v;
        zs += __expf(v - mh);
    }
    red[t] = zs;
    __syncthreads();
    #pragma unroll
    for (int off = 128; off >= 8; off >>= 1) {
        if (t < off) red[t] += red[t + off];
        __syncthreads();
    }
    if (t < 8) rz_s[t] = 1.0f / (red[t] + 1e-16f);
    __syncthreads();

    int half = t >> 7, c4 = t & 127;
    float4 acc[8];
    #pragma unroll
    for (int hh = 0; hh < 8; hh++) acc[hh] = make_float4(0.f, 0.f, 0.f, 0.f);

    for (int eb = 0; eb < ne + 1; eb += 32) {
        int nn = min(32, ne + 1 - eb);
        __syncthreads();
        if (t < nn * 8) {
            int el = t >> 3, hh = t & 7;
            int s = (eb + el < ne) ? csr[e0 + eb + el] : d;
            if (hh == 0) sl[el] = s;
            float v = asrc[s * 8 + hh] + adst[d * 8 + hh];
            v = v > 0.f ? v : 0.2f * v;
            al[t] = __expf(v - m_s[hh]) * rz_s[hh];
        }
        __syncthreads();
        for (int el = half; el < nn; el += 2) {
            int s = sl[el];
            float4 v = *(const float4*)(hl0 + ((size_t)s << 9) + 4 * c4);
            float4 a0 = *(const float4*)&al[el * 8];
            float4 a1 = *(const float4*)&al[el * 8 + 4];
            float av[8] = {a0.x, a0.y, a0.z, a0.w, a1.x, a1.y, a1.z, a1.w};
            #pragma unroll
            for (int hh = 0; hh < 8; hh++) {
                acc[hh].x = fmaf(av[hh], v.x, acc[hh].x);
                acc[hh].y = fmaf(av[hh], v.y, acc[hh].y);
                acc[hh].z = fmaf(av[hh], v.z, acc[hh].z);
                acc[hh].w = fmaf(av[hh], v.w, acc[hh].w);
            }
        }
    }
    if (half) {
        #pragma unroll
        for (int hh = 0; hh < 8; hh++) *(float4*)&comb1[hh][c4 * 4] = acc[hh];
    }
    __syncthreads();
    if (!half) {
        #pragma unroll
        for (int hh = 0; hh < 8; hh++) {
            float4 c2 = *(const float4*)&comb1[hh][c4 * 4];
            float4 v;
            v.x = acc[hh].x + c2.x;
            v.y = acc[hh].y + c2.y;
            v.z = acc[hh].z + c2.z;
            v.w = acc[hh].w + c2.w;
            u16 hx[4], lx[4];
            split2(v.x, hx[0], lx[0]);
            split2(v.y, hx[1], lx[1]);
            split2(v.z, hx[2], lx[2]);
            split2(v.w, hx[3], lx[3]);
            size_t ob = (size_t)dl * 4096 + hh * 512 + 4 * c4;
            *(ushort4*)(aggh + ob) = make_ushort4(hx[0], hx[1], hx[2], hx[3]);
            *(ushort4*)(aggl + ob) = make_ushort4(lx[0], lx[1], lx[2], lx[3]);
        }
    }
}

// ------------------------------- launcher ----------------------------------
extern "C" void kernel_launch(void* const* d_in, const int* in_sizes, int n_in,
                              void* d_out, int out_size, void* d_ws, size_t ws_size,
                              hipStream_t stream) {
    const float* x = (const float*)d_in[0];
    const int* ei = (const int*)d_in[1];
    const float* W0 = (const float*)d_in[2];
    const float* at_s0 = (const float*)d_in[3];
    const float* at_d0 = (const float*)d_in[4];
    const float* b0 = (const float*)d_in[5];
    const float* W1 = (const float*)d_in[6];
    const float* at_s1 = (const float*)d_in[7];
    const float* at_d1 = (const float*)d_in[8];
    const float* b1 = (const float*)d_in[9];
    float* out = (float*)d_out;

    const int N = NNODES;
    const int E = in_sizes[1] / 2;
    const int* esrc = ei;
    const int* edst = ei + E;

    char* p = (char*)d_ws;
    auto carve = [&](size_t bytes) -> void* {
        void* r = (void*)p;
        p += ((bytes + 255) & ~(size_t)255);
        return r;
    };
    float* h0 = (float*)carve((size_t)N * 512 * 4);   // aliased by P in layer 1
    float* hl0 = (float*)carve((size_t)N * 512 * 4);
    float* as0 = (float*)carve((size_t)N * 8 * 4);
    float* ad0 = (float*)carve((size_t)N * 8 * 4);
    float* as1 = (float*)carve((size_t)N * 8 * 4);
    float* ad1 = (float*)carve((size_t)N * 8 * 4);
    int* deg = (int*)carve((size_t)N * 4);
    int* indptr = (int*)carve((size_t)(N + 1) * 4);
    int* cursor = (int*)carve((size_t)N * 4);
    int* csr = (int*)carve((size_t)E * 4);
    float* ws1 = (float*)carve(512 * 8 * 4);
    float* wd1 = (float*)carve(512 * 8 * 4);
    u16* xh = (u16*)carve((size_t)N * 512 * 2);
    u16* xl = (u16*)carve((size_t)N * 512 * 2);
    u16* W0h = (u16*)carve((size_t)512 * 512 * 2);
    u16* W0l = (u16*)carve((size_t)512 * 512 * 2);
    u16* B1h = (u16*)carve((size_t)512 * 4096 * 2);
    u16* B1l = (u16*)carve((size_t)512 * 4096 * 2);
    size_t used = (size_t)(p - (char*)d_ws);

    // chunk size: only agg (16 KB/node); partials P alias h0 (dead in layer 1)
    int CH = 1024;
    const int cands[5] = {16384, 8192, 4096, 2048, 1024};
    for (int ci = 0; ci < 5; ci++) {
        if (ws_size >= used + (size_t)cands[ci] * 16384 + 512) {
            CH = cands[ci];
            break;
        }
    }
    if (CH > 8192) CH = 8192;    // NS>=2 keeps grid at >=512 blocks
    u16* aggh = (u16*)carve((size_t)CH * 4096 * 2);
    u16* aggl = (u16*)carve((size_t)CH * 4096 * 2);
    float* P = h0;               // NS*CH*512 floats <= N*512 floats = |h0|
    int NS = N / CH;             // K-split factor -> grid always 512 blocks

    // CSR build
    zero_k<<<(N + 255) / 256, 256, 0, stream>>>(deg, N);
    count_k<<<(E + 255) / 256, 256, 0, stream>>>(edst, E, deg);
    scan_k<<<1, 1024, 0, stream>>>(deg, indptr, cursor, N);
    scatter_k<<<(E + 255) / 256, 256, 0, stream>>>(esrc, edst, E, cursor, csr);

    // operand prep (split bf16, coalesced tiled transposes) + folded weights
    prepx_k<<<(N * 512 / 4 + 255) / 256, 256, 0, stream>>>(x, xh, xl);
    prepW0t_k<<<64, 256, 0, stream>>>(W0, W0h, W0l);
    prepW1t_k<<<512, 256, 0, stream>>>(W1, B1h, B1l);
    prep1_k<<<512, 256, 0, stream>>>(W1, at_s1, at_d1, ws1, wd1);

    // Layer 0
    mgemm4_k<0><<<dim3(4, N / 128), 256, 0, stream>>>(
        xh, xl, W0h, W0l, h0, 512, nullptr);
    alpha0_k<<<N / 4, 256, 0, stream>>>(h0, at_s0, at_d0, as0, ad0);
    node0_k<<<N, 256, 0, stream>>>(h0, as0, ad0, indptr, csr, b0, ws1, wd1,
                                   hl0, as1, ad1);

    // Layer 1: aggregate per chunk, K-split GEMM into P, combine(+b1, ELU)
    for (int base = 0; base < N; base += CH) {
        node1_k<<<CH, 256, 0, stream>>>(hl0, as1, ad1, indptr, csr, aggh, aggl,
                                        base, CH);
        mgemm4_k<1><<<dim3(4, CH / 128, NS), 256, 0, stream>>>(
            aggh, aggl, B1h, B1l, nullptr, 4096, P);
        combine_k<<<CH / 2, 256, 0, stream>>>(P, b1, out + (size_t)base * 512,
                                              CH, NS);
    }
}

// Round 9
// 560.036 us; speedup vs baseline: 1.8981x; 1.8981x over previous
//
#include <hip/hip_runtime.h>
#include <hip/hip_bf16.h>

// ---------------------------------------------------------------------------
// GAT 2-layer, N=16384 nodes, D=512, H=8, E=524288 edges (+self loops)
// GEMMs: round-5-proven split-bf16 MFMA 16x16x32, BM=64/BN=128, XOR-swizzled
// LDS + global_load_lds. Layer-0: 3-term (A 2-plane). Layer-1: 2-term with
// single-plane bf16 aggregate (A-side) -- 33% fewer MFMA on the big GEMM.
// Node kernels: CSR softmax + float4 gather, XCD-pinned. alpha1 fused.
// ---------------------------------------------------------------------------

#define NNODES 16384

typedef unsigned short u16;
typedef unsigned int u32;
typedef __attribute__((ext_vector_type(8))) __bf16 bf16x8;
typedef __attribute__((ext_vector_type(4))) float f32x4;

__device__ __forceinline__ u16 f2bf(float v) {
    u32 u = __builtin_bit_cast(u32, v);
    u32 r = (u + 0x7fffu + ((u >> 16) & 1u)) >> 16;
    return (u16)r;
}
__device__ __forceinline__ float bf2f(u16 s) {
    u32 u = ((u32)s) << 16;
    return __builtin_bit_cast(float, u);
}
__device__ __forceinline__ void split2(float v, u16& h, u16& l) {
    h = f2bf(v);
    l = f2bf(v - bf2f(h));
}

// async global->LDS, 16B per lane; LDS dest is wave-uniform base + lane*16
__device__ __forceinline__ void gload_lds16(const u16* g, u16* l) {
    __builtin_amdgcn_global_load_lds(
        (__attribute__((address_space(1))) void*)(void*)(g),
        (__attribute__((address_space(3))) void*)(void*)(l), 16, 0, 0);
}

// ------------------------------ CSR build ---------------------------------
__global__ void zero_k(int* p, int n) {
    int i = blockIdx.x * 256 + threadIdx.x;
    if (i < n) p[i] = 0;
}

__global__ void count_k(const int* __restrict__ dst, int E, int* __restrict__ deg) {
    int i = blockIdx.x * 256 + threadIdx.x;
    if (i < E) atomicAdd(&deg[dst[i]], 1);
}

__global__ __launch_bounds__(1024) void scan_k(const int* __restrict__ deg,
                                               int* __restrict__ indptr,
                                               int* __restrict__ cursor, int n) {
    __shared__ int sums[1024];
    int t = threadIdx.x;
    int base = t * 16;
    int local[16];
    int s = 0;
    #pragma unroll
    for (int i = 0; i < 16; i++) { local[i] = s; s += deg[base + i]; }
    sums[t] = s;
    __syncthreads();
    for (int off = 1; off < 1024; off <<= 1) {
        int v = (t >= off) ? sums[t - off] : 0;
        __syncthreads();
        sums[t] += v;
        __syncthreads();
    }
    int base_sum = (t == 0) ? 0 : sums[t - 1];
    #pragma unroll
    for (int i = 0; i < 16; i++) {
        int v = base_sum + local[i];
        indptr[base + i] = v;
        cursor[base + i] = v;
    }
    if (t == 1023) indptr[n] = base_sum + s;
}

__global__ void scatter_k(const int* __restrict__ src, const int* __restrict__ dst,
                          int E, int* __restrict__ cursor, int* __restrict__ csr) {
    int i = blockIdx.x * 256 + threadIdx.x;
    if (i < E) {
        int pos = atomicAdd(&cursor[dst[i]], 1);
        csr[pos] = src[i];
    }
}

// ------------------------- split-bf16 prep kernels -------------------------
__global__ void prepx_k(const float* __restrict__ x, u16* __restrict__ xh,
                        u16* __restrict__ xl) {
    int idx = blockIdx.x * 256 + threadIdx.x;
    int e = idx << 2;
    int n = e >> 9, k = e & 511;
    int g = n >> 10, s = n & 1023;
    float4 v = *(const float4*)(x + ((size_t)(s * 16 + g) << 9) + k);
    u16 h[4], l[4];
    split2(v.x, h[0], l[0]);
    split2(v.y, h[1], l[1]);
    split2(v.z, h[2], l[2]);
    split2(v.w, h[3], l[3]);
    size_t o = ((size_t)n << 9) + k;
    *(ushort4*)(xh + o) = make_ushort4(h[0], h[1], h[2], h[3]);
    *(ushort4*)(xl + o) = make_ushort4(l[0], l[1], l[2], l[3]);
}

// W0t[n][k] = W0[k][n], tiled 64x64 transpose through LDS
__global__ __launch_bounds__(256) void prepW0t_k(const float* __restrict__ W0,
                                                 u16* __restrict__ Wh,
                                                 u16* __restrict__ Wl) {
    __shared__ u32 tile[64][65];
    int b = blockIdx.x;
    int kt = (b >> 3) * 64, nt = (b & 7) * 64;
    int t = threadIdx.x;
    #pragma unroll
    for (int i = 0; i < 16; i++) {
        int idx = i * 256 + t;
        int r = idx >> 6, c = idx & 63;
        float v = W0[(size_t)(kt + r) * 512 + nt + c];
        u16 h, l;
        split2(v, h, l);
        tile[r][c] = ((u32)h << 16) | l;
    }
    __syncthreads();
    #pragma unroll
    for (int i = 0; i < 8; i++) {
        int idx = i * 256 + t;
        int r = idx >> 5, c2 = (idx & 31) * 2;
        u32 p0 = tile[c2][r], p1 = tile[c2 + 1][r];
        size_t o = (size_t)(nt + r) * 512 + kt + c2;
        *(ushort2*)(Wh + o) = make_ushort2((u16)(p0 >> 16), (u16)(p1 >> 16));
        *(ushort2*)(Wl + o) = make_ushort2((u16)(p0 & 0xffff), (u16)(p1 & 0xffff));
    }
}

// B1t[c][h*512+k] = W1[k][h*512+c]/8, per-head tiled 64x64 transpose
__global__ __launch_bounds__(256) void prepW1t_k(const float* __restrict__ W1,
                                                 u16* __restrict__ Bh,
                                                 u16* __restrict__ Bl) {
    __shared__ u32 tile[64][65];
    int b = blockIdx.x;
    int hh = b >> 6;
    int rem = b & 63;
    int kt = (rem >> 3) * 64, ct = (rem & 7) * 64;
    int t = threadIdx.x;
    #pragma unroll
    for (int i = 0; i < 16; i++) {
        int idx = i * 256 + t;
        int r = idx >> 6, c = idx & 63;
        float v = W1[(size_t)(kt + r) * 4096 + hh * 512 + ct + c] * 0.125f;
        u16 h, l;
        split2(v, h, l);
        tile[r][c] = ((u32)h << 16) | l;
    }
    __syncthreads();
    #pragma unroll
    for (int i = 0; i < 8; i++) {
        int idx = i * 256 + t;
        int r = idx >> 5, c2 = (idx & 31) * 2;
        u32 p0 = tile[c2][r], p1 = tile[c2 + 1][r];
        size_t o = (size_t)(ct + r) * 4096 + hh * 512 + kt + c2;
        *(ushort2*)(Bh + o) = make_ushort2((u16)(p0 >> 16), (u16)(p1 >> 16));
        *(ushort2*)(Bl + o) = make_ushort2((u16)(p0 & 0xffff), (u16)(p1 & 0xffff));
    }
}

// ---------------------------------------------------------------------------
// Split-bf16 MFMA GEMM (round-5-proven structure): C[M,512] = A[M,K]@Bt[512,K]^T
// BM=64, BN=128, BK=32, 4 waves (2x2; wave = 32 rows x 64 cols, acc[2][4]).
// global_load_lds staging, XOR-swizzled k-slot on source + ds_read (T21).
// TERMS=3: A has hi+lo planes (Ah,Al), 3 MFMA per frag pair.
// TERMS=2: A single bf16 plane (Ah), 2 MFMA per frag pair.
// MODE 1: epilogue +bias, ELU.
// ---------------------------------------------------------------------------
template <int MODE, int TERMS>
__global__ __launch_bounds__(256) void mgemm_k(
    const u16* __restrict__ Ah, const u16* __restrict__ Al,
    const u16* __restrict__ Bh, const u16* __restrict__ Bl,
    float* __restrict__ C, int K, const float* __restrict__ bias) {
    constexpr int pAl = 2048;                       // TERMS=3 only
    constexpr int pBh = (TERMS == 3) ? 4096 : 2048;
    constexpr int pBl = (TERMS == 3) ? 8192 : 6144;
    __shared__ u16 smem[(TERMS == 3) ? 12288 : 10240];

    int t = threadIdx.x;
    int lane = t & 63, w = t >> 6;
    int wr = w >> 1, wc = w & 1;
    int row0 = blockIdx.y * 64, col0 = blockIdx.x * 128;

    f32x4 acc[2][4];
    #pragma unroll
    for (int i = 0; i < 2; i++)
        #pragma unroll
        for (int j = 0; j < 4; j++) acc[i][j] = (f32x4){0.f, 0.f, 0.f, 0.f};

    int srow = lane >> 2;          // row within 16-row segment
    int sl4 = lane & 3;            // 16B slot within 64B row
    int rl = lane & 15, kb = lane >> 4;

    for (int k0 = 0; k0 < K; k0 += 32) {
        // ---- async stage (linear LDS dest, swizzled global source slot) ----
        if (TERMS == 3) {
            const u16* gb;
            int po, nseg, g0;
            if (w == 0) { gb = Ah; po = 0; nseg = 4; g0 = row0; }
            else if (w == 1) { gb = Al; po = pAl; nseg = 4; g0 = row0; }
            else if (w == 2) { gb = Bh; po = pBh; nseg = 8; g0 = col0; }
            else { gb = Bl; po = pBl; nseg = 8; g0 = col0; }
            #pragma unroll
            for (int sgi = 0; sgi < 8; sgi++) {
                if (sgi < nseg) {
                    int row = sgi * 16 + srow;
                    int slot = sl4 ^ ((row >> 1) & 3);
                    gload_lds16(gb + (size_t)(g0 + row) * K + k0 + slot * 8,
                                smem + po + sgi * 512);
                }
            }
        } else {
            // 20 segments (A:4, Bh:8, Bl:8), 5 per wave
            #pragma unroll
            for (int ii = 0; ii < 5; ii++) {
                int s = w * 5 + ii;
                const u16* gb;
                int po, seg, g0;
                if (s < 4) { gb = Ah; po = 0; seg = s; g0 = row0; }
                else if (s < 12) { gb = Bh; po = pBh; seg = s - 4; g0 = col0; }
                else { gb = Bl; po = pBl; seg = s - 12; g0 = col0; }
                int row = seg * 16 + srow;
                int slot = sl4 ^ ((row >> 1) & 3);
                gload_lds16(gb + (size_t)(g0 + row) * K + k0 + slot * 8,
                            smem + po + seg * 512);
            }
        }
        __syncthreads();   // vmcnt(0) drain before barrier

        // ---- fragments (swizzled ds_read_b128) ----
        bf16x8 af[2], afl_[2], bfh[4], bfl[4];
        #pragma unroll
        for (int f = 0; f < 2; f++) {
            int r = wr * 32 + rl + f * 16;
            int off = r * 32 + ((kb ^ ((r >> 1) & 3)) << 3);
            af[f] = *(const bf16x8*)(smem + off);
            if (TERMS == 3) afl_[f] = *(const bf16x8*)(smem + pAl + off);
        }
        #pragma unroll
        for (int j = 0; j < 4; j++) {
            int r = wc * 64 + rl + j * 16;
            int off = r * 32 + ((kb ^ ((r >> 1) & 3)) << 3);
            bfh[j] = *(const bf16x8*)(smem + pBh + off);
            bfl[j] = *(const bf16x8*)(smem + pBl + off);
        }
        #pragma unroll
        for (int i = 0; i < 2; i++)
            #pragma unroll
            for (int j = 0; j < 4; j++) {
                if (TERMS == 3)
                    acc[i][j] = __builtin_amdgcn_mfma_f32_16x16x32_bf16(
                        afl_[i], bfh[j], acc[i][j], 0, 0, 0);
                acc[i][j] = __builtin_amdgcn_mfma_f32_16x16x32_bf16(
                    af[i], bfl[j], acc[i][j], 0, 0, 0);
                acc[i][j] = __builtin_amdgcn_mfma_f32_16x16x32_bf16(
                    af[i], bfh[j], acc[i][j], 0, 0, 0);
            }
        __syncthreads();
    }

    int cr = kb * 4;
    #pragma unroll
    for (int i = 0; i < 2; i++) {
        #pragma unroll
        for (int j = 0; j < 4; j++) {
            int col = col0 + wc * 64 + j * 16 + rl;
            float bv = (MODE == 1) ? bias[col] : 0.f;
            f32x4 v = acc[i][j];
            #pragma unroll
            for (int q = 0; q < 4; q++) {
                float o = v[q] + bv;
                if (MODE == 1) o = o > 0.f ? o : __expf(o) - 1.f;
                size_t grow = (size_t)(row0 + wr * 32 + i * 16 + cr + q);
                C[grow * 512 + col] = o;
            }
        }
    }
}

// ------------------------------ attention ---------------------------------
__global__ __launch_bounds__(256) void alpha0_k(const float* __restrict__ h0,
                                                const float* __restrict__ att_s,
                                                const float* __restrict__ att_d,
                                                float* __restrict__ as_,
                                                float* __restrict__ ad_) {
    int n = blockIdx.x * 4 + (threadIdx.x >> 6);
    int l = threadIdx.x & 63;
    int h = l >> 3, i = l & 7;
    float ps = 0.f, pd = 0.f;
    #pragma unroll
    for (int c = 0; c < 64; c += 8) {
        float v = h0[(size_t)n * 512 + h * 64 + c + i];
        ps += v * att_s[h * 64 + c + i];
        pd += v * att_d[h * 64 + c + i];
    }
    #pragma unroll
    for (int off = 1; off < 8; off <<= 1) {
        ps += __shfl_xor(ps, off);
        pd += __shfl_xor(pd, off);
    }
    if (i == 0) {
        as_[n * 8 + h] = ps;
        ad_[n * 8 + h] = pd;
    }
}

__global__ __launch_bounds__(256) void prep1_k(const float* __restrict__ W1,
                                               const float* __restrict__ as1,
                                               const float* __restrict__ ad1,
                                               float* __restrict__ ws1,
                                               float* __restrict__ wd1) {
    int k = blockIdx.x;
    int t = threadIdx.x;
    int h = t >> 5, lane = t & 31;
    float ps = 0.f, pd = 0.f;
    for (int c = lane; c < 512; c += 32) {
        float w = W1[(size_t)k * 4096 + h * 512 + c];
        ps += w * as1[h * 512 + c];
        pd += w * ad1[h * 512 + c];
    }
    #pragma unroll
    for (int off = 1; off < 32; off <<= 1) {
        ps += __shfl_xor(ps, off);
        pd += __shfl_xor(pd, off);
    }
    if (lane == 0) {
        ws1[k * 8 + h] = ps;
        wd1[k * 8 + h] = pd;
    }
}

// -------- layer-0 node kernel: softmax + aggregate + ELU + fused alpha1 ----
__global__ __launch_bounds__(256) void node0_k(
    const float* __restrict__ h0, const float* __restrict__ asrc,
    const float* __restrict__ adst, const int* __restrict__ indptr,
    const int* __restrict__ csr, const float* __restrict__ b0,
    const float* __restrict__ ws1, const float* __restrict__ wd1,
    float* __restrict__ hl0, float* __restrict__ as1, float* __restrict__ ad1) {
    int d = (blockIdx.x & 7) * (NNODES / 8) + (blockIdx.x >> 3);
    int t = threadIdx.x;
    __shared__ float red[256];
    __shared__ float m_s[8], rz_s[8];
    __shared__ float al[32 * 8];
    __shared__ int sl[32];
    __shared__ float comb[128 * 4];
    __shared__ float pw[2][16];
    int e0 = indptr[d], ne = indptr[d + 1] - e0;
    int h = t & 7, slice = t >> 3;
    float adh = adst[d * 8 + h];

    float mx = -3.0e38f;
    for (int e = slice; e < ne + 1; e += 32) {
        int s = (e < ne) ? csr[e0 + e] : d;
        float v = asrc[s * 8 + h] + adh;
        v = v > 0.f ? v : 0.2f * v;
        mx = fmaxf(mx, v);
    }
    red[t] = mx;
    __syncthreads();
    #pragma unroll
    for (int off = 128; off >= 8; off >>= 1) {
        if (t < off) red[t] = fmaxf(red[t], red[t + off]);
        __syncthreads();
    }
    if (t < 8) m_s[t] = red[t];
    __syncthreads();

    float mh = m_s[h];
    float zs = 0.f;
    for (int e = slice; e < ne + 1; e += 32) {
        int s = (e < ne) ? csr[e0 + e] : d;
        float v = asrc[s * 8 + h] + adh;
        v = v > 0.f ? v : 0.2f * v;
        zs += __expf(v - mh);
    }
    red[t] = zs;
    __syncthreads();
    #pragma unroll
    for (int off = 128; off >= 8; off >>= 1) {
        if (t < off) red[t] += red[t + off];
        __syncthreads();
    }
    if (t < 8) rz_s[t] = 1.0f / (red[t] + 1e-16f);
    __syncthreads();

    int half = t >> 7, c4 = t & 127;
    int hc = c4 >> 4;
    float4 acc4 = make_float4(0.f, 0.f, 0.f, 0.f);
    for (int eb = 0; eb < ne + 1; eb += 32) {
        int nn = min(32, ne + 1 - eb);
        __syncthreads();
        if (t < nn * 8) {  // t = el*8 + hh
            int el = t >> 3, hh = t & 7;
            int s = (eb + el < ne) ? csr[e0 + eb + el] : d;
            if (hh == 0) sl[el] = s;
            float v = asrc[s * 8 + hh] + adst[d * 8 + hh];
            v = v > 0.f ? v : 0.2f * v;
            al[t] = __expf(v - m_s[hh]) * rz_s[hh];
        }
        __syncthreads();
        for (int el = half; el < nn; el += 2) {
            int s = sl[el];
            float a = al[el * 8 + hc];
            float4 v = *(const float4*)(h0 + ((size_t)s << 9) + 4 * c4);
            acc4.x = fmaf(a, v.x, acc4.x);
            acc4.y = fmaf(a, v.y, acc4.y);
            acc4.z = fmaf(a, v.z, acc4.z);
            acc4.w = fmaf(a, v.w, acc4.w);
        }
    }
    if (half) *(float4*)&comb[c4 * 4] = acc4;
    __syncthreads();
    if (!half) {
        float4 c2 = *(const float4*)&comb[c4 * 4];
        float4 bv = *(const float4*)(b0 + 4 * c4);
        float4 o;
        o.x = acc4.x + c2.x + bv.x;
        o.y = acc4.y + c2.y + bv.y;
        o.z = acc4.z + c2.z + bv.z;
        o.w = acc4.w + c2.w + bv.w;
        o.x = o.x > 0.f ? o.x : __expf(o.x) - 1.f;
        o.y = o.y > 0.f ? o.y : __expf(o.y) - 1.f;
        o.z = o.z > 0.f ? o.z : __expf(o.z) - 1.f;
        o.w = o.w > 0.f ? o.w : __expf(o.w) - 1.f;
        *(float4*)(hl0 + ((size_t)d << 9) + 4 * c4) = o;

        float ps[8] = {}, pd[8] = {};
        float oq[4] = {o.x, o.y, o.z, o.w};
        #pragma unroll
        for (int q = 0; q < 4; q++) {
            const float4* w4 = (const float4*)(ws1 + (size_t)(4 * c4 + q) * 8);
            const float4* v4 = (const float4*)(wd1 + (size_t)(4 * c4 + q) * 8);
            float4 wa = w4[0], wb = w4[1];
            float4 va = v4[0], vb = v4[1];
            ps[0] = fmaf(oq[q], wa.x, ps[0]);
            ps[1] = fmaf(oq[q], wa.y, ps[1]);
            ps[2] = fmaf(oq[q], wa.z, ps[2]);
            ps[3] = fmaf(oq[q], wa.w, ps[3]);
            ps[4] = fmaf(oq[q], wb.x, ps[4]);
            ps[5] = fmaf(oq[q], wb.y, ps[5]);
            ps[6] = fmaf(oq[q], wb.z, ps[6]);
            ps[7] = fmaf(oq[q], wb.w, ps[7]);
            pd[0] = fmaf(oq[q], va.x, pd[0]);
            pd[1] = fmaf(oq[q], va.y, pd[1]);
            pd[2] = fmaf(oq[q], va.z, pd[2]);
            pd[3] = fmaf(oq[q], va.w, pd[3]);
            pd[4] = fmaf(oq[q], vb.x, pd[4]);
            pd[5] = fmaf(oq[q], vb.y, pd[5]);
            pd[6] = fmaf(oq[q], vb.z, pd[6]);
            pd[7] = fmaf(oq[q], vb.w, pd[7]);
        }
        #pragma unroll
        for (int off = 1; off < 64; off <<= 1) {
            #pragma unroll
            for (int hh = 0; hh < 8; hh++) {
                ps[hh] += __shfl_xor(ps[hh], off);
                pd[hh] += __shfl_xor(pd[hh], off);
            }
        }
        if ((t & 63) == 0) {
            int wv = t >> 6;
            #pragma unroll
            for (int hh = 0; hh < 8; hh++) {
                pw[wv][hh] = ps[hh];
                pw[wv][8 + hh] = pd[hh];
            }
        }
    }
    __syncthreads();
    if (t < 8) as1[(size_t)d * 8 + t] = pw[0][t] + pw[1][t];
    else if (t < 16) ad1[(size_t)d * 8 + t - 8] = pw[0][t] + pw[1][t];
}

// ---- layer-1 node kernel: softmax + per-head aggregate -> bf16 (1 plane) ---
__global__ __launch_bounds__(256) void node1_k(const float* __restrict__ hl0,
                                               const float* __restrict__ asrc,
                                               const float* __restrict__ adst,
                                               const int* __restrict__ indptr,
                                               const int* __restrict__ csr,
                                               u16* __restrict__ aggh,
                                               int base, int ch) {
    int dl = (blockIdx.x & 7) * (ch >> 3) + (blockIdx.x >> 3);
    int d = base + dl;
    int t = threadIdx.x;
    __shared__ float red[256];
    __shared__ float m_s[8], rz_s[8];
    __shared__ float al[32 * 8];
    __shared__ int sl[32];
    __shared__ float comb1[8][128 * 4];
    int e0 = indptr[d], ne = indptr[d + 1] - e0;
    int h = t & 7, slice = t >> 3;
    float adh = adst[d * 8 + h];

    float mx = -3.0e38f;
    for (int e = slice; e < ne + 1; e += 32) {
        int s = (e < ne) ? csr[e0 + e] : d;
        float v = asrc[s * 8 + h] + adh;
        v = v > 0.f ? v : 0.2f * v;
        mx = fmaxf(mx, v);
    }
    red[t] = mx;
    __syncthreads();
    #pragma unroll
    for (int off = 128; off >= 8; off >>= 1) {
        if (t < off) red[t] = fmaxf(red[t], red[t + off]);
        __syncthreads();
    }
    if (t < 8) m_s[t] = red[t];
    __syncthreads();

    float mh = m_s[h];
    float zs = 0.f;
    for (int e = slice; e < ne + 1; e += 32) {
        int s = (e < ne) ? csr[e0 + e] : d;
        float v = asrc[s * 8 + h] + adh;
        v = v > 0.f ? v : 0.2f * v;
        zs += __expf(v - mh);
    }
    red[t] = zs;
    __syncthreads();
    #pragma unroll
    for (int off = 128; off >= 8; off >>= 1) {
        if (t < off) red[t] += red[t + off];
        __syncthreads();
    }
    if (t < 8) rz_s[t] = 1.0f / (red[t] + 1e-16f);
    __syncthreads();

    int half = t >> 7, c4 = t & 127;
    float4 acc[8];
    #pragma unroll
    for (int hh = 0; hh < 8; hh++) acc[hh] = make_float4(0.f, 0.f, 0.f, 0.f);

    for (int eb = 0; eb < ne + 1; eb += 32) {
        int nn = min(32, ne + 1 - eb);
        __syncthreads();
        if (t < nn * 8) {
            int el = t >> 3, hh = t & 7;
            int s = (eb + el < ne) ? csr[e0 + eb + el] : d;
            if (hh == 0) sl[el] = s;
            float v = asrc[s * 8 + hh] + adst[d * 8 + hh];
            v = v > 0.f ? v : 0.2f * v;
            al[t] = __expf(v - m_s[hh]) * rz_s[hh];
        }
        __syncthreads();
        for (int el = half; el < nn; el += 2) {
            int s = sl[el];
            float4 v = *(const float4*)(hl0 + ((size_t)s << 9) + 4 * c4);
            float4 a0 = *(const float4*)&al[el * 8];
            float4 a1 = *(const float4*)&al[el * 8 + 4];
            float av[8] = {a0.x, a0.y, a0.z, a0.w, a1.x, a1.y, a1.z, a1.w};
            #pragma unroll
            for (int hh = 0; hh < 8; hh++) {
                acc[hh].x = fmaf(av[hh], v.x, acc[hh].x);
                acc[hh].y = fmaf(av[hh], v.y, acc[hh].y);
                acc[hh].z = fmaf(av[hh], v.z, acc[hh].z);
                acc[hh].w = fmaf(av[hh], v.w, acc[hh].w);
            }
        }
    }
    if (half) {
        #pragma unroll
        for (int hh = 0; hh < 8; hh++) *(float4*)&comb1[hh][c4 * 4] = acc[hh];
    }
    __syncthreads();
    if (!half) {
        #pragma unroll
        for (int hh = 0; hh < 8; hh++) {
            float4 c2 = *(const float4*)&comb1[hh][c4 * 4];
            u16 hx[4];
            hx[0] = f2bf(acc[hh].x + c2.x);
            hx[1] = f2bf(acc[hh].y + c2.y);
            hx[2] = f2bf(acc[hh].z + c2.z);
            hx[3] = f2bf(acc[hh].w + c2.w);
            size_t ob = (size_t)dl * 4096 + hh * 512 + 4 * c4;
            *(ushort4*)(aggh + ob) = make_ushort4(hx[0], hx[1], hx[2], hx[3]);
        }
    }
}

// ------------------------------- launcher ----------------------------------
extern "C" void kernel_launch(void* const* d_in, const int* in_sizes, int n_in,
                              void* d_out, int out_size, void* d_ws, size_t ws_size,
                              hipStream_t stream) {
    const float* x = (const float*)d_in[0];
    const int* ei = (const int*)d_in[1];
    const float* W0 = (const float*)d_in[2];
    const float* at_s0 = (const float*)d_in[3];
    const float* at_d0 = (const float*)d_in[4];
    const float* b0 = (const float*)d_in[5];
    const float* W1 = (const float*)d_in[6];
    const float* at_s1 = (const float*)d_in[7];
    const float* at_d1 = (const float*)d_in[8];
    const float* b1 = (const float*)d_in[9];
    float* out = (float*)d_out;

    const int N = NNODES;
    const int E = in_sizes[1] / 2;
    const int* esrc = ei;
    const int* edst = ei + E;

    char* p = (char*)d_ws;
    auto carve = [&](size_t bytes) -> void* {
        void* r = (void*)p;
        p += ((bytes + 255) & ~(size_t)255);
        return r;
    };
    float* h0 = (float*)carve((size_t)N * 512 * 4);
    float* hl0 = (float*)carve((size_t)N * 512 * 4);
    float* as0 = (float*)carve((size_t)N * 8 * 4);
    float* ad0 = (float*)carve((size_t)N * 8 * 4);
    float* as1 = (float*)carve((size_t)N * 8 * 4);
    float* ad1 = (float*)carve((size_t)N * 8 * 4);
    int* deg = (int*)carve((size_t)N * 4);
    int* indptr = (int*)carve((size_t)(N + 1) * 4);
    int* cursor = (int*)carve((size_t)N * 4);
    int* csr = (int*)carve((size_t)E * 4);
    float* ws1 = (float*)carve(512 * 8 * 4);
    float* wd1 = (float*)carve(512 * 8 * 4);
    u16* xh = (u16*)carve((size_t)N * 512 * 2);
    u16* xl = (u16*)carve((size_t)N * 512 * 2);
    u16* W0h = (u16*)carve((size_t)512 * 512 * 2);
    u16* W0l = (u16*)carve((size_t)512 * 512 * 2);
    u16* B1h = (u16*)carve((size_t)512 * 4096 * 2);
    u16* B1l = (u16*)carve((size_t)512 * 4096 * 2);
    size_t used = (size_t)(p - (char*)d_ws);

    // chunk size: agg is now 8 KB/node (single bf16 plane)
    int CH = 1024;
    const int cands[5] = {16384, 8192, 4096, 2048, 1024};
    for (int ci = 0; ci < 5; ci++) {
        if (ws_size >= used + (size_t)cands[ci] * 8192 + 512) {
            CH = cands[ci];
            break;
        }
    }
    u16* aggh = (u16*)carve((size_t)CH * 4096 * 2);

    // CSR build
    zero_k<<<(N + 255) / 256, 256, 0, stream>>>(deg, N);
    count_k<<<(E + 255) / 256, 256, 0, stream>>>(edst, E, deg);
    scan_k<<<1, 1024, 0, stream>>>(deg, indptr, cursor, N);
    scatter_k<<<(E + 255) / 256, 256, 0, stream>>>(esrc, edst, E, cursor, csr);

    // operand prep (split bf16) + folded layer-1 attention weights
    prepx_k<<<(N * 512 / 4 + 255) / 256, 256, 0, stream>>>(x, xh, xl);
    prepW0t_k<<<64, 256, 0, stream>>>(W0, W0h, W0l);
    prepW1t_k<<<512, 256, 0, stream>>>(W1, B1h, B1l);
    prep1_k<<<512, 256, 0, stream>>>(W1, at_s1, at_d1, ws1, wd1);

    // Layer 0 (3-term split GEMM, round-5 structure)
    mgemm_k<0, 3><<<dim3(4, N / 64), 256, 0, stream>>>(
        xh, xl, W0h, W0l, h0, 512, nullptr);
    alpha0_k<<<N / 4, 256, 0, stream>>>(h0, at_s0, at_d0, as0, ad0);
    node0_k<<<N, 256, 0, stream>>>(h0, as0, ad0, indptr, csr, b0, ws1, wd1,
                                   hl0, as1, ad1);

    // Layer 1: bf16 aggregate per chunk, 2-term fused GEMM (+b1, ELU)
    for (int base = 0; base < N; base += CH) {
        node1_k<<<CH, 256, 0, stream>>>(hl0, as1, ad1, indptr, csr, aggh,
                                        base, CH);
        mgemm_k<1, 2><<<dim3(4, CH / 64), 256, 0, stream>>>(
            aggh, nullptr, B1h, B1l, out + (size_t)base * 512, 4096, b1);
    }
}

// Round 10
// 524.941 us; speedup vs baseline: 2.0250x; 1.0669x over previous
//
#include <hip/hip_runtime.h>
#include <hip/hip_bf16.h>

// ---------------------------------------------------------------------------
// GAT 2-layer, N=16384 nodes, D=512, H=8, E=524288 edges (+self loops)
// GEMMs: split-bf16 MFMA 16x16x32, BM=BN=128 (m97 tile), acc[4][4]/wave,
// XOR-swizzled LDS + global_load_lds (16-rows/seg staging, 4 lanes/row),
// hoisted staging pointers. Layer-0: 3-term. Layer-1: 2-term, bf16 agg.
// Node kernels: CSR softmax + float4 gather, XCD-pinned. alpha1 fused.
// ---------------------------------------------------------------------------

#define NNODES 16384

typedef unsigned short u16;
typedef unsigned int u32;
typedef __attribute__((ext_vector_type(8))) __bf16 bf16x8;
typedef __attribute__((ext_vector_type(4))) float f32x4;

__device__ __forceinline__ u16 f2bf(float v) {
    u32 u = __builtin_bit_cast(u32, v);
    u32 r = (u + 0x7fffu + ((u >> 16) & 1u)) >> 16;
    return (u16)r;
}
__device__ __forceinline__ float bf2f(u16 s) {
    u32 u = ((u32)s) << 16;
    return __builtin_bit_cast(float, u);
}
__device__ __forceinline__ void split2(float v, u16& h, u16& l) {
    h = f2bf(v);
    l = f2bf(v - bf2f(h));
}

// async global->LDS, 16B per lane; LDS dest is wave-uniform base + lane*16
__device__ __forceinline__ void gload_lds16(const u16* g, u16* l) {
    __builtin_amdgcn_global_load_lds(
        (__attribute__((address_space(1))) void*)(void*)(g),
        (__attribute__((address_space(3))) void*)(void*)(l), 16, 0, 0);
}

// ------------------------------ CSR build ---------------------------------
__global__ void zero_k(int* p, int n) {
    int i = blockIdx.x * 256 + threadIdx.x;
    if (i < n) p[i] = 0;
}

__global__ void count_k(const int* __restrict__ dst, int E, int* __restrict__ deg) {
    int i = blockIdx.x * 256 + threadIdx.x;
    if (i < E) atomicAdd(&deg[dst[i]], 1);
}

__global__ __launch_bounds__(1024) void scan_k(const int* __restrict__ deg,
                                               int* __restrict__ indptr,
                                               int* __restrict__ cursor, int n) {
    __shared__ int sums[1024];
    int t = threadIdx.x;
    int base = t * 16;
    int local[16];
    int s = 0;
    #pragma unroll
    for (int i = 0; i < 16; i++) { local[i] = s; s += deg[base + i]; }
    sums[t] = s;
    __syncthreads();
    for (int off = 1; off < 1024; off <<= 1) {
        int v = (t >= off) ? sums[t - off] : 0;
        __syncthreads();
        sums[t] += v;
        __syncthreads();
    }
    int base_sum = (t == 0) ? 0 : sums[t - 1];
    #pragma unroll
    for (int i = 0; i < 16; i++) {
        int v = base_sum + local[i];
        indptr[base + i] = v;
        cursor[base + i] = v;
    }
    if (t == 1023) indptr[n] = base_sum + s;
}

__global__ void scatter_k(const int* __restrict__ src, const int* __restrict__ dst,
                          int E, int* __restrict__ cursor, int* __restrict__ csr) {
    int i = blockIdx.x * 256 + threadIdx.x;
    if (i < E) {
        int pos = atomicAdd(&cursor[dst[i]], 1);
        csr[pos] = src[i];
    }
}

// ------------------------- split-bf16 prep kernels -------------------------
__global__ void prepx_k(const float* __restrict__ x, u16* __restrict__ xh,
                        u16* __restrict__ xl) {
    int idx = blockIdx.x * 256 + threadIdx.x;
    int e = idx << 2;
    int n = e >> 9, k = e & 511;
    int g = n >> 10, s = n & 1023;
    float4 v = *(const float4*)(x + ((size_t)(s * 16 + g) << 9) + k);
    u16 h[4], l[4];
    split2(v.x, h[0], l[0]);
    split2(v.y, h[1], l[1]);
    split2(v.z, h[2], l[2]);
    split2(v.w, h[3], l[3]);
    size_t o = ((size_t)n << 9) + k;
    *(ushort4*)(xh + o) = make_ushort4(h[0], h[1], h[2], h[3]);
    *(ushort4*)(xl + o) = make_ushort4(l[0], l[1], l[2], l[3]);
}

// W0t[n][k] = W0[k][n], tiled 64x64 transpose through LDS
__global__ __launch_bounds__(256) void prepW0t_k(const float* __restrict__ W0,
                                                 u16* __restrict__ Wh,
                                                 u16* __restrict__ Wl) {
    __shared__ u32 tile[64][65];
    int b = blockIdx.x;
    int kt = (b >> 3) * 64, nt = (b & 7) * 64;
    int t = threadIdx.x;
    #pragma unroll
    for (int i = 0; i < 16; i++) {
        int idx = i * 256 + t;
        int r = idx >> 6, c = idx & 63;
        float v = W0[(size_t)(kt + r) * 512 + nt + c];
        u16 h, l;
        split2(v, h, l);
        tile[r][c] = ((u32)h << 16) | l;
    }
    __syncthreads();
    #pragma unroll
    for (int i = 0; i < 8; i++) {
        int idx = i * 256 + t;
        int r = idx >> 5, c2 = (idx & 31) * 2;
        u32 p0 = tile[c2][r], p1 = tile[c2 + 1][r];
        size_t o = (size_t)(nt + r) * 512 + kt + c2;
        *(ushort2*)(Wh + o) = make_ushort2((u16)(p0 >> 16), (u16)(p1 >> 16));
        *(ushort2*)(Wl + o) = make_ushort2((u16)(p0 & 0xffff), (u16)(p1 & 0xffff));
    }
}

// B1t[c][h*512+k] = W1[k][h*512+c]/8, per-head tiled 64x64 transpose
__global__ __launch_bounds__(256) void prepW1t_k(const float* __restrict__ W1,
                                                 u16* __restrict__ Bh,
                                                 u16* __restrict__ Bl) {
    __shared__ u32 tile[64][65];
    int b = blockIdx.x;
    int hh = b >> 6;
    int rem = b & 63;
    int kt = (rem >> 3) * 64, ct = (rem & 7) * 64;
    int t = threadIdx.x;
    #pragma unroll
    for (int i = 0; i < 16; i++) {
        int idx = i * 256 + t;
        int r = idx >> 6, c = idx & 63;
        float v = W1[(size_t)(kt + r) * 4096 + hh * 512 + ct + c] * 0.125f;
        u16 h, l;
        split2(v, h, l);
        tile[r][c] = ((u32)h << 16) | l;
    }
    __syncthreads();
    #pragma unroll
    for (int i = 0; i < 8; i++) {
        int idx = i * 256 + t;
        int r = idx >> 5, c2 = (idx & 31) * 2;
        u32 p0 = tile[c2][r], p1 = tile[c2 + 1][r];
        size_t o = (size_t)(ct + r) * 4096 + hh * 512 + kt + c2;
        *(ushort2*)(Bh + o) = make_ushort2((u16)(p0 >> 16), (u16)(p1 >> 16));
        *(ushort2*)(Bl + o) = make_ushort2((u16)(p0 & 0xffff), (u16)(p1 & 0xffff));
    }
}

// ---------------------------------------------------------------------------
// Split-bf16 MFMA GEMM: C[M,512] = A[M,K] @ Bt[512,K]^T
// BM=BN=128, BK=32, 4 waves (2x2; wave = 64x64, acc[4][4] = 16 chains),
// 16x16x32 MFMA. Staging: 1KB segments of 16 rows x (4 lanes/row x 16B),
// XOR-swizzled k-slot on global source + ds_read (T21); per-wave segment
// pointers hoisted out of the K-loop (static unroll -> registers).
// TERMS=3: A 2-plane (Ah,Al). TERMS=2: A 1-plane. MODE 1: +bias, ELU.
// ---------------------------------------------------------------------------
template <int MODE, int TERMS>
__global__ __launch_bounds__(256) void mgemm_k(
    const u16* __restrict__ Ah, const u16* __restrict__ Al,
    const u16* __restrict__ Bh, const u16* __restrict__ Bl,
    float* __restrict__ C, int K, const float* __restrict__ bias) {
    constexpr int pAl = 4096;                        // TERMS=3 only
    constexpr int pBh = (TERMS == 3) ? 8192 : 4096;
    constexpr int pBl = (TERMS == 3) ? 12288 : 8192;
    constexpr int NSEG = (TERMS == 3) ? 8 : 6;       // segments per wave
    __shared__ u16 smem[(TERMS == 3) ? 16384 : 12288];

    int t = threadIdx.x;
    int lane = t & 63, w = t >> 6;
    int wr = w >> 1, wc = w & 1;
    int row0 = blockIdx.y * 128, col0 = blockIdx.x * 128;

    f32x4 acc[4][4];
    #pragma unroll
    for (int i = 0; i < 4; i++)
        #pragma unroll
        for (int j = 0; j < 4; j++) acc[i][j] = (f32x4){0.f, 0.f, 0.f, 0.f};

    // hoisted staging pointers: seg s covers 16 rows, 4 lanes per row
    int srow = lane >> 2;          // row within segment
    int sl4 = lane & 3;            // 16B slot within 64B row
    const u16* gp[NSEG];
    u16* lp[NSEG];
    #pragma unroll
    for (int ii = 0; ii < NSEG; ii++) {
        int s = w * NSEG + ii;     // wave-uniform
        int pl = s >> 3, seg = s & 7;
        const u16* gb;
        int g0;
        if (TERMS == 3) {
            gb = (pl == 0) ? Ah : (pl == 1) ? Al : (pl == 2) ? Bh : Bl;
            g0 = (pl < 2) ? row0 : col0;
        } else {
            gb = (pl == 0) ? Ah : (pl == 1) ? Bh : Bl;
            g0 = (pl == 0) ? row0 : col0;
        }
        int row = seg * 16 + srow;
        int slot = sl4 ^ ((row >> 1) & 3);
        gp[ii] = gb + (size_t)(g0 + row) * K + slot * 8;
        lp[ii] = smem + pl * 4096 + seg * 512;
    }

    int rl = lane & 15, kb = lane >> 4;

    for (int k0 = 0; k0 < K; k0 += 32) {
        #pragma unroll
        for (int ii = 0; ii < NSEG; ii++) gload_lds16(gp[ii] + k0, lp[ii]);
        __syncthreads();   // vmcnt(0) drain before barrier

        bf16x8 afh[4], afl_[4], bfh[4], bfl[4];
        #pragma unroll
        for (int f = 0; f < 4; f++) {
            int r = wr * 64 + f * 16 + rl;
            int off = r * 32 + ((kb ^ ((r >> 1) & 3)) << 3);
            afh[f] = *(const bf16x8*)(smem + off);
            if (TERMS == 3) afl_[f] = *(const bf16x8*)(smem + pAl + off);
        }
        #pragma unroll
        for (int j = 0; j < 4; j++) {
            int r = wc * 64 + j * 16 + rl;
            int off = r * 32 + ((kb ^ ((r >> 1) & 3)) << 3);
            bfh[j] = *(const bf16x8*)(smem + pBh + off);
            bfl[j] = *(const bf16x8*)(smem + pBl + off);
        }
        #pragma unroll
        for (int i = 0; i < 4; i++)
            #pragma unroll
            for (int j = 0; j < 4; j++) {
                if (TERMS == 3)
                    acc[i][j] = __builtin_amdgcn_mfma_f32_16x16x32_bf16(
                        afl_[i], bfh[j], acc[i][j], 0, 0, 0);
                acc[i][j] = __builtin_amdgcn_mfma_f32_16x16x32_bf16(
                    afh[i], bfl[j], acc[i][j], 0, 0, 0);
                acc[i][j] = __builtin_amdgcn_mfma_f32_16x16x32_bf16(
                    afh[i], bfh[j], acc[i][j], 0, 0, 0);
            }
        __syncthreads();
    }

    // C/D layout 16x16: col = lane&15, row = (lane>>4)*4 + q
    int cr = kb * 4;
    #pragma unroll
    for (int i = 0; i < 4; i++) {
        #pragma unroll
        for (int j = 0; j < 4; j++) {
            int col = col0 + wc * 64 + j * 16 + rl;
            float bv = (MODE == 1) ? bias[col] : 0.f;
            f32x4 v = acc[i][j];
            #pragma unroll
            for (int q = 0; q < 4; q++) {
                float o = v[q] + bv;
                if (MODE == 1) o = o > 0.f ? o : __expf(o) - 1.f;
                size_t grow = (size_t)(row0 + wr * 64 + i * 16 + cr + q);
                C[grow * 512 + col] = o;
            }
        }
    }
}

// ------------------------------ attention ---------------------------------
__global__ __launch_bounds__(256) void alpha0_k(const float* __restrict__ h0,
                                                const float* __restrict__ att_s,
                                                const float* __restrict__ att_d,
                                                float* __restrict__ as_,
                                                float* __restrict__ ad_) {
    int n = blockIdx.x * 4 + (threadIdx.x >> 6);
    int l = threadIdx.x & 63;
    int h = l >> 3, i = l & 7;
    float ps = 0.f, pd = 0.f;
    #pragma unroll
    for (int c = 0; c < 64; c += 8) {
        float v = h0[(size_t)n * 512 + h * 64 + c + i];
        ps += v * att_s[h * 64 + c + i];
        pd += v * att_d[h * 64 + c + i];
    }
    #pragma unroll
    for (int off = 1; off < 8; off <<= 1) {
        ps += __shfl_xor(ps, off);
        pd += __shfl_xor(pd, off);
    }
    if (i == 0) {
        as_[n * 8 + h] = ps;
        ad_[n * 8 + h] = pd;
    }
}

__global__ __launch_bounds__(256) void prep1_k(const float* __restrict__ W1,
                                               const float* __restrict__ as1,
                                               const float* __restrict__ ad1,
                                               float* __restrict__ ws1,
                                               float* __restrict__ wd1) {
    int k = blockIdx.x;
    int t = threadIdx.x;
    int h = t >> 5, lane = t & 31;
    float ps = 0.f, pd = 0.f;
    for (int c = lane; c < 512; c += 32) {
        float w = W1[(size_t)k * 4096 + h * 512 + c];
        ps += w * as1[h * 512 + c];
        pd += w * ad1[h * 512 + c];
    }
    #pragma unroll
    for (int off = 1; off < 32; off <<= 1) {
        ps += __shfl_xor(ps, off);
        pd += __shfl_xor(pd, off);
    }
    if (lane == 0) {
        ws1[k * 8 + h] = ps;
        wd1[k * 8 + h] = pd;
    }
}

// -------- layer-0 node kernel: softmax + aggregate + ELU + fused alpha1 ----
__global__ __launch_bounds__(256) void node0_k(
    const float* __restrict__ h0, const float* __restrict__ asrc,
    const float* __restrict__ adst, const int* __restrict__ indptr,
    const int* __restrict__ csr, const float* __restrict__ b0,
    const float* __restrict__ ws1, const float* __restrict__ wd1,
    float* __restrict__ hl0, float* __restrict__ as1, float* __restrict__ ad1) {
    int d = (blockIdx.x & 7) * (NNODES / 8) + (blockIdx.x >> 3);
    int t = threadIdx.x;
    __shared__ float red[256];
    __shared__ float m_s[8], rz_s[8];
    __shared__ float al[32 * 8];
    __shared__ int sl[32];
    __shared__ float comb[128 * 4];
    __shared__ float pw[2][16];
    int e0 = indptr[d], ne = indptr[d + 1] - e0;
    int h = t & 7, slice = t >> 3;
    float adh = adst[d * 8 + h];

    float mx = -3.0e38f;
    for (int e = slice; e < ne + 1; e += 32) {
        int s = (e < ne) ? csr[e0 + e] : d;
        float v = asrc[s * 8 + h] + adh;
        v = v > 0.f ? v : 0.2f * v;
        mx = fmaxf(mx, v);
    }
    red[t] = mx;
    __syncthreads();
    #pragma unroll
    for (int off = 128; off >= 8; off >>= 1) {
        if (t < off) red[t] = fmaxf(red[t], red[t + off]);
        __syncthreads();
    }
    if (t < 8) m_s[t] = red[t];
    __syncthreads();

    float mh = m_s[h];
    float zs = 0.f;
    for (int e = slice; e < ne + 1; e += 32) {
        int s = (e < ne) ? csr[e0 + e] : d;
        float v = asrc[s * 8 + h] + adh;
        v = v > 0.f ? v : 0.2f * v;
        zs += __expf(v - mh);
    }
    red[t] = zs;
    __syncthreads();
    #pragma unroll
    for (int off = 128; off >= 8; off >>= 1) {
        if (t < off) red[t] += red[t + off];
        __syncthreads();
    }
    if (t < 8) rz_s[t] = 1.0f / (red[t] + 1e-16f);
    __syncthreads();

    int half = t >> 7, c4 = t & 127;
    int hc = c4 >> 4;
    float4 acc4 = make_float4(0.f, 0.f, 0.f, 0.f);
    for (int eb = 0; eb < ne + 1; eb += 32) {
        int nn = min(32, ne + 1 - eb);
        __syncthreads();
        if (t < nn * 8) {  // t = el*8 + hh
            int el = t >> 3, hh = t & 7;
            int s = (eb + el < ne) ? csr[e0 + eb + el] : d;
            if (hh == 0) sl[el] = s;
            float v = asrc[s * 8 + hh] + adst[d * 8 + hh];
            v = v > 0.f ? v : 0.2f * v;
            al[t] = __expf(v - m_s[hh]) * rz_s[hh];
        }
        __syncthreads();
        for (int el = half; el < nn; el += 2) {
            int s = sl[el];
            float a = al[el * 8 + hc];
            float4 v = *(const float4*)(h0 + ((size_t)s << 9) + 4 * c4);
            acc4.x = fmaf(a, v.x, acc4.x);
            acc4.y = fmaf(a, v.y, acc4.y);
            acc4.z = fmaf(a, v.z, acc4.z);
            acc4.w = fmaf(a, v.w, acc4.w);
        }
    }
    if (half) *(float4*)&comb[c4 * 4] = acc4;
    __syncthreads();
    if (!half) {
        float4 c2 = *(const float4*)&comb[c4 * 4];
        float4 bv = *(const float4*)(b0 + 4 * c4);
        float4 o;
        o.x = acc4.x + c2.x + bv.x;
        o.y = acc4.y + c2.y + bv.y;
        o.z = acc4.z + c2.z + bv.z;
        o.w = acc4.w + c2.w + bv.w;
        o.x = o.x > 0.f ? o.x : __expf(o.x) - 1.f;
        o.y = o.y > 0.f ? o.y : __expf(o.y) - 1.f;
        o.z = o.z > 0.f ? o.z : __expf(o.z) - 1.f;
        o.w = o.w > 0.f ? o.w : __expf(o.w) - 1.f;
        *(float4*)(hl0 + ((size_t)d << 9) + 4 * c4) = o;

        float ps[8] = {}, pd[8] = {};
        float oq[4] = {o.x, o.y, o.z, o.w};
        #pragma unroll
        for (int q = 0; q < 4; q++) {
            const float4* w4 = (const float4*)(ws1 + (size_t)(4 * c4 + q) * 8);
            const float4* v4 = (const float4*)(wd1 + (size_t)(4 * c4 + q) * 8);
            float4 wa = w4[0], wb = w4[1];
            float4 va = v4[0], vb = v4[1];
            ps[0] = fmaf(oq[q], wa.x, ps[0]);
            ps[1] = fmaf(oq[q], wa.y, ps[1]);
            ps[2] = fmaf(oq[q], wa.z, ps[2]);
            ps[3] = fmaf(oq[q], wa.w, ps[3]);
            ps[4] = fmaf(oq[q], wb.x, ps[4]);
            ps[5] = fmaf(oq[q], wb.y, ps[5]);
            ps[6] = fmaf(oq[q], wb.z, ps[6]);
            ps[7] = fmaf(oq[q], wb.w, ps[7]);
            pd[0] = fmaf(oq[q], va.x, pd[0]);
            pd[1] = fmaf(oq[q], va.y, pd[1]);
            pd[2] = fmaf(oq[q], va.z, pd[2]);
            pd[3] = fmaf(oq[q], va.w, pd[3]);
            pd[4] = fmaf(oq[q], vb.x, pd[4]);
            pd[5] = fmaf(oq[q], vb.y, pd[5]);
            pd[6] = fmaf(oq[q], vb.z, pd[6]);
            pd[7] = fmaf(oq[q], vb.w, pd[7]);
        }
        #pragma unroll
        for (int off = 1; off < 64; off <<= 1) {
            #pragma unroll
            for (int hh = 0; hh < 8; hh++) {
                ps[hh] += __shfl_xor(ps[hh], off);
                pd[hh] += __shfl_xor(pd[hh], off);
            }
        }
        if ((t & 63) == 0) {
            int wv = t >> 6;
            #pragma unroll
            for (int hh = 0; hh < 8; hh++) {
                pw[wv][hh] = ps[hh];
                pw[wv][8 + hh] = pd[hh];
            }
        }
    }
    __syncthreads();
    if (t < 8) as1[(size_t)d * 8 + t] = pw[0][t] + pw[1][t];
    else if (t < 16) ad1[(size_t)d * 8 + t - 8] = pw[0][t] + pw[1][t];
}

// ---- layer-1 node kernel: softmax + per-head aggregate -> bf16 (1 plane) ---
__global__ __launch_bounds__(256) void node1_k(const float* __restrict__ hl0,
                                               const float* __restrict__ asrc,
                                               const float* __restrict__ adst,
                                               const int* __restrict__ indptr,
                                               const int* __restrict__ csr,
                                               u16* __restrict__ aggh,
                                               int base, int ch) {
    int dl = (blockIdx.x & 7) * (ch >> 3) + (blockIdx.x >> 3);
    int d = base + dl;
    int t = threadIdx.x;
    __shared__ float red[256];
    __shared__ float m_s[8], rz_s[8];
    __shared__ float al[32 * 8];
    __shared__ int sl[32];
    __shared__ float comb1[8][128 * 4];
    int e0 = indptr[d], ne = indptr[d + 1] - e0;
    int h = t & 7, slice = t >> 3;
    float adh = adst[d * 8 + h];

    float mx = -3.0e38f;
    for (int e = slice; e < ne + 1; e += 32) {
        int s = (e < ne) ? csr[e0 + e] : d;
        float v = asrc[s * 8 + h] + adh;
        v = v > 0.f ? v : 0.2f * v;
        mx = fmaxf(mx, v);
    }
    red[t] = mx;
    __syncthreads();
    #pragma unroll
    for (int off = 128; off >= 8; off >>= 1) {
        if (t < off) red[t] = fmaxf(red[t], red[t + off]);
        __syncthreads();
    }
    if (t < 8) m_s[t] = red[t];
    __syncthreads();

    float mh = m_s[h];
    float zs = 0.f;
    for (int e = slice; e < ne + 1; e += 32) {
        int s = (e < ne) ? csr[e0 + e] : d;
        float v = asrc[s * 8 + h] + adh;
        v = v > 0.f ? v : 0.2f * v;
        zs += __expf(v - mh);
    }
    red[t] = zs;
    __syncthreads();
    #pragma unroll
    for (int off = 128; off >= 8; off >>= 1) {
        if (t < off) red[t] += red[t + off];
        __syncthreads();
    }
    if (t < 8) rz_s[t] = 1.0f / (red[t] + 1e-16f);
    __syncthreads();

    int half = t >> 7, c4 = t & 127;
    float4 acc[8];
    #pragma unroll
    for (int hh = 0; hh < 8; hh++) acc[hh] = make_float4(0.f, 0.f, 0.f, 0.f);

    for (int eb = 0; eb < ne + 1; eb += 32) {
        int nn = min(32, ne + 1 - eb);
        __syncthreads();
        if (t < nn * 8) {
            int el = t >> 3, hh = t & 7;
            int s = (eb + el < ne) ? csr[e0 + eb + el] : d;
            if (hh == 0) sl[el] = s;
            float v = asrc[s * 8 + hh] + adst[d * 8 + hh];
            v = v > 0.f ? v : 0.2f * v;
            al[t] = __expf(v - m_s[hh]) * rz_s[hh];
        }
        __syncthreads();
        for (int el = half; el < nn; el += 2) {
            int s = sl[el];
            float4 v = *(const float4*)(hl0 + ((size_t)s << 9) + 4 * c4);
            float4 a0 = *(const float4*)&al[el * 8];
            float4 a1 = *(const float4*)&al[el * 8 + 4];
            float av[8] = {a0.x, a0.y, a0.z, a0.w, a1.x, a1.y, a1.z, a1.w};
            #pragma unroll
            for (int hh = 0; hh < 8; hh++) {
                acc[hh].x = fmaf(av[hh], v.x, acc[hh].x);
                acc[hh].y = fmaf(av[hh], v.y, acc[hh].y);
                acc[hh].z = fmaf(av[hh], v.z, acc[hh].z);
                acc[hh].w = fmaf(av[hh], v.w, acc[hh].w);
            }
        }
    }
    if (half) {
        #pragma unroll
        for (int hh = 0; hh < 8; hh++) *(float4*)&comb1[hh][c4 * 4] = acc[hh];
    }
    __syncthreads();
    if (!half) {
        #pragma unroll
        for (int hh = 0; hh < 8; hh++) {
            float4 c2 = *(const float4*)&comb1[hh][c4 * 4];
            u16 hx[4];
            hx[0] = f2bf(acc[hh].x + c2.x);
            hx[1] = f2bf(acc[hh].y + c2.y);
            hx[2] = f2bf(acc[hh].z + c2.z);
            hx[3] = f2bf(acc[hh].w + c2.w);
            size_t ob = (size_t)dl * 4096 + hh * 512 + 4 * c4;
            *(ushort4*)(aggh + ob) = make_ushort4(hx[0], hx[1], hx[2], hx[3]);
        }
    }
}

// ------------------------------- launcher ----------------------------------
extern "C" void kernel_launch(void* const* d_in, const int* in_sizes, int n_in,
                              void* d_out, int out_size, void* d_ws, size_t ws_size,
                              hipStream_t stream) {
    const float* x = (const float*)d_in[0];
    const int* ei = (const int*)d_in[1];
    const float* W0 = (const float*)d_in[2];
    const float* at_s0 = (const float*)d_in[3];
    const float* at_d0 = (const float*)d_in[4];
    const float* b0 = (const float*)d_in[5];
    const float* W1 = (const float*)d_in[6];
    const float* at_s1 = (const float*)d_in[7];
    const float* at_d1 = (const float*)d_in[8];
    const float* b1 = (const float*)d_in[9];
    float* out = (float*)d_out;

    const int N = NNODES;
    const int E = in_sizes[1] / 2;
    const int* esrc = ei;
    const int* edst = ei + E;

    char* p = (char*)d_ws;
    auto carve = [&](size_t bytes) -> void* {
        void* r = (void*)p;
        p += ((bytes + 255) & ~(size_t)255);
        return r;
    };
    float* h0 = (float*)carve((size_t)N * 512 * 4);
    float* hl0 = (float*)carve((size_t)N * 512 * 4);
    float* as0 = (float*)carve((size_t)N * 8 * 4);
    float* ad0 = (float*)carve((size_t)N * 8 * 4);
    float* as1 = (float*)carve((size_t)N * 8 * 4);
    float* ad1 = (float*)carve((size_t)N * 8 * 4);
    int* deg = (int*)carve((size_t)N * 4);
    int* indptr = (int*)carve((size_t)(N + 1) * 4);
    int* cursor = (int*)carve((size_t)N * 4);
    int* csr = (int*)carve((size_t)E * 4);
    float* ws1 = (float*)carve(512 * 8 * 4);
    float* wd1 = (float*)carve(512 * 8 * 4);
    u16* xh = (u16*)carve((size_t)N * 512 * 2);
    u16* xl = (u16*)carve((size_t)N * 512 * 2);
    u16* W0h = (u16*)carve((size_t)512 * 512 * 2);
    u16* W0l = (u16*)carve((size_t)512 * 512 * 2);
    u16* B1h = (u16*)carve((size_t)512 * 4096 * 2);
    u16* B1l = (u16*)carve((size_t)512 * 4096 * 2);
    size_t used = (size_t)(p - (char*)d_ws);

    // chunk size: agg is 8 KB/node (single bf16 plane); CH multiple of 128
    int CH = 1024;
    const int cands[5] = {16384, 8192, 4096, 2048, 1024};
    for (int ci = 0; ci < 5; ci++) {
        if (ws_size >= used + (size_t)cands[ci] * 8192 + 512) {
            CH = cands[ci];
            break;
        }
    }
    u16* aggh = (u16*)carve((size_t)CH * 4096 * 2);

    // CSR build
    zero_k<<<(N + 255) / 256, 256, 0, stream>>>(deg, N);
    count_k<<<(E + 255) / 256, 256, 0, stream>>>(edst, E, deg);
    scan_k<<<1, 1024, 0, stream>>>(deg, indptr, cursor, N);
    scatter_k<<<(E + 255) / 256, 256, 0, stream>>>(esrc, edst, E, cursor, csr);

    // operand prep (split bf16) + folded layer-1 attention weights
    prepx_k<<<(N * 512 / 4 + 255) / 256, 256, 0, stream>>>(x, xh, xl);
    prepW0t_k<<<64, 256, 0, stream>>>(W0, W0h, W0l);
    prepW1t_k<<<512, 256, 0, stream>>>(W1, B1h, B1l);
    prep1_k<<<512, 256, 0, stream>>>(W1, at_s1, at_d1, ws1, wd1);

    // Layer 0 (3-term split GEMM, 128x128 tile)
    mgemm_k<0, 3><<<dim3(4, N / 128), 256, 0, stream>>>(
        xh, xl, W0h, W0l, h0, 512, nullptr);
    alpha0_k<<<N / 4, 256, 0, stream>>>(h0, at_s0, at_d0, as0, ad0);
    node0_k<<<N, 256, 0, stream>>>(h0, as0, ad0, indptr, csr, b0, ws1, wd1,
                                   hl0, as1, ad1);

    // Layer 1: bf16 aggregate per chunk, 2-term fused GEMM (+b1, ELU)
    for (int base = 0; base < N; base += CH) {
        node1_k<<<CH, 256, 0, stream>>>(hl0, as1, ad1, indptr, csr, aggh,
                                        base, CH);
        mgemm_k<1, 2><<<dim3(4, CH / 128), 256, 0, stream>>>(
            aggh, nullptr, B1h, B1l, out + (size_t)base * 512, 4096, b1);
    }
}

// Round 11
// 519.747 us; speedup vs baseline: 2.0452x; 1.0100x over previous
//
#include <hip/hip_runtime.h>
#include <hip/hip_bf16.h>

// ---------------------------------------------------------------------------
// GAT 2-layer, N=16384 nodes, D=512, H=8, E=524288 edges (+self loops)
// GEMMs: split-bf16 MFMA 16x16x32, BM=BN=128, XOR-swizzled global_load_lds
// (round-10 proven, untouched). Node kernels: ONE WAVE PER NODE, barrier-free
// online softmax + shfl-distributed CSR gather. alpha1 fused into node0.
// ---------------------------------------------------------------------------

#define NNODES 16384

typedef unsigned short u16;
typedef unsigned int u32;
typedef __attribute__((ext_vector_type(8))) __bf16 bf16x8;
typedef __attribute__((ext_vector_type(4))) float f32x4;

__device__ __forceinline__ u16 f2bf(float v) {
    u32 u = __builtin_bit_cast(u32, v);
    u32 r = (u + 0x7fffu + ((u >> 16) & 1u)) >> 16;
    return (u16)r;
}
__device__ __forceinline__ float bf2f(u16 s) {
    u32 u = ((u32)s) << 16;
    return __builtin_bit_cast(float, u);
}
__device__ __forceinline__ void split2(float v, u16& h, u16& l) {
    h = f2bf(v);
    l = f2bf(v - bf2f(h));
}

// async global->LDS, 16B per lane
__device__ __forceinline__ void gload_lds16(const u16* g, u16* l) {
    __builtin_amdgcn_global_load_lds(
        (__attribute__((address_space(1))) void*)(void*)(g),
        (__attribute__((address_space(3))) void*)(void*)(l), 16, 0, 0);
}

// ------------------------------ CSR build ---------------------------------
__global__ void zero_k(int* p, int n) {
    int i = blockIdx.x * 256 + threadIdx.x;
    if (i < n) p[i] = 0;
}

__global__ void count_k(const int* __restrict__ dst, int E, int* __restrict__ deg) {
    int i = blockIdx.x * 256 + threadIdx.x;
    if (i < E) atomicAdd(&deg[dst[i]], 1);
}

__global__ __launch_bounds__(1024) void scan_k(const int* __restrict__ deg,
                                               int* __restrict__ indptr,
                                               int* __restrict__ cursor, int n) {
    __shared__ int sums[1024];
    int t = threadIdx.x;
    int base = t * 16;
    int local[16];
    int s = 0;
    #pragma unroll
    for (int i = 0; i < 16; i++) { local[i] = s; s += deg[base + i]; }
    sums[t] = s;
    __syncthreads();
    for (int off = 1; off < 1024; off <<= 1) {
        int v = (t >= off) ? sums[t - off] : 0;
        __syncthreads();
        sums[t] += v;
        __syncthreads();
    }
    int base_sum = (t == 0) ? 0 : sums[t - 1];
    #pragma unroll
    for (int i = 0; i < 16; i++) {
        int v = base_sum + local[i];
        indptr[base + i] = v;
        cursor[base + i] = v;
    }
    if (t == 1023) indptr[n] = base_sum + s;
}

__global__ void scatter_k(const int* __restrict__ src, const int* __restrict__ dst,
                          int E, int* __restrict__ cursor, int* __restrict__ csr) {
    int i = blockIdx.x * 256 + threadIdx.x;
    if (i < E) {
        int pos = atomicAdd(&cursor[dst[i]], 1);
        csr[pos] = src[i];
    }
}

// ------------------------- split-bf16 prep kernels -------------------------
__global__ void prepx_k(const float* __restrict__ x, u16* __restrict__ xh,
                        u16* __restrict__ xl) {
    int idx = blockIdx.x * 256 + threadIdx.x;
    int e = idx << 2;
    int n = e >> 9, k = e & 511;
    int g = n >> 10, s = n & 1023;
    float4 v = *(const float4*)(x + ((size_t)(s * 16 + g) << 9) + k);
    u16 h[4], l[4];
    split2(v.x, h[0], l[0]);
    split2(v.y, h[1], l[1]);
    split2(v.z, h[2], l[2]);
    split2(v.w, h[3], l[3]);
    size_t o = ((size_t)n << 9) + k;
    *(ushort4*)(xh + o) = make_ushort4(h[0], h[1], h[2], h[3]);
    *(ushort4*)(xl + o) = make_ushort4(l[0], l[1], l[2], l[3]);
}

// W0t[n][k] = W0[k][n], tiled 64x64 transpose through LDS
__global__ __launch_bounds__(256) void prepW0t_k(const float* __restrict__ W0,
                                                 u16* __restrict__ Wh,
                                                 u16* __restrict__ Wl) {
    __shared__ u32 tile[64][65];
    int b = blockIdx.x;
    int kt = (b >> 3) * 64, nt = (b & 7) * 64;
    int t = threadIdx.x;
    #pragma unroll
    for (int i = 0; i < 16; i++) {
        int idx = i * 256 + t;
        int r = idx >> 6, c = idx & 63;
        float v = W0[(size_t)(kt + r) * 512 + nt + c];
        u16 h, l;
        split2(v, h, l);
        tile[r][c] = ((u32)h << 16) | l;
    }
    __syncthreads();
    #pragma unroll
    for (int i = 0; i < 8; i++) {
        int idx = i * 256 + t;
        int r = idx >> 5, c2 = (idx & 31) * 2;
        u32 p0 = tile[c2][r], p1 = tile[c2 + 1][r];
        size_t o = (size_t)(nt + r) * 512 + kt + c2;
        *(ushort2*)(Wh + o) = make_ushort2((u16)(p0 >> 16), (u16)(p1 >> 16));
        *(ushort2*)(Wl + o) = make_ushort2((u16)(p0 & 0xffff), (u16)(p1 & 0xffff));
    }
}

// B1t[c][h*512+k] = W1[k][h*512+c]/8, per-head tiled 64x64 transpose
__global__ __launch_bounds__(256) void prepW1t_k(const float* __restrict__ W1,
                                                 u16* __restrict__ Bh,
                                                 u16* __restrict__ Bl) {
    __shared__ u32 tile[64][65];
    int b = blockIdx.x;
    int hh = b >> 6;
    int rem = b & 63;
    int kt = (rem >> 3) * 64, ct = (rem & 7) * 64;
    int t = threadIdx.x;
    #pragma unroll
    for (int i = 0; i < 16; i++) {
        int idx = i * 256 + t;
        int r = idx >> 6, c = idx & 63;
        float v = W1[(size_t)(kt + r) * 4096 + hh * 512 + ct + c] * 0.125f;
        u16 h, l;
        split2(v, h, l);
        tile[r][c] = ((u32)h << 16) | l;
    }
    __syncthreads();
    #pragma unroll
    for (int i = 0; i < 8; i++) {
        int idx = i * 256 + t;
        int r = idx >> 5, c2 = (idx & 31) * 2;
        u32 p0 = tile[c2][r], p1 = tile[c2 + 1][r];
        size_t o = (size_t)(ct + r) * 4096 + hh * 512 + kt + c2;
        *(ushort2*)(Bh + o) = make_ushort2((u16)(p0 >> 16), (u16)(p1 >> 16));
        *(ushort2*)(Bl + o) = make_ushort2((u16)(p0 & 0xffff), (u16)(p1 & 0xffff));
    }
}

// ---------------------------------------------------------------------------
// Split-bf16 MFMA GEMM (round-10, UNCHANGED): C[M,512] = A[M,K] @ Bt[512,K]^T
// ---------------------------------------------------------------------------
template <int MODE, int TERMS>
__global__ __launch_bounds__(256) void mgemm_k(
    const u16* __restrict__ Ah, const u16* __restrict__ Al,
    const u16* __restrict__ Bh, const u16* __restrict__ Bl,
    float* __restrict__ C, int K, const float* __restrict__ bias) {
    constexpr int pAl = 4096;
    constexpr int pBh = (TERMS == 3) ? 8192 : 4096;
    constexpr int pBl = (TERMS == 3) ? 12288 : 8192;
    constexpr int NSEG = (TERMS == 3) ? 8 : 6;
    __shared__ u16 smem[(TERMS == 3) ? 16384 : 12288];

    int t = threadIdx.x;
    int lane = t & 63, w = t >> 6;
    int wr = w >> 1, wc = w & 1;
    int row0 = blockIdx.y * 128, col0 = blockIdx.x * 128;

    f32x4 acc[4][4];
    #pragma unroll
    for (int i = 0; i < 4; i++)
        #pragma unroll
        for (int j = 0; j < 4; j++) acc[i][j] = (f32x4){0.f, 0.f, 0.f, 0.f};

    int srow = lane >> 2;
    int sl4 = lane & 3;
    const u16* gp[NSEG];
    u16* lp[NSEG];
    #pragma unroll
    for (int ii = 0; ii < NSEG; ii++) {
        int s = w * NSEG + ii;
        int pl = s >> 3, seg = s & 7;
        const u16* gb;
        int g0;
        if (TERMS == 3) {
            gb = (pl == 0) ? Ah : (pl == 1) ? Al : (pl == 2) ? Bh : Bl;
            g0 = (pl < 2) ? row0 : col0;
        } else {
            gb = (pl == 0) ? Ah : (pl == 1) ? Bh : Bl;
            g0 = (pl == 0) ? row0 : col0;
        }
        int row = seg * 16 + srow;
        int slot = sl4 ^ ((row >> 1) & 3);
        gp[ii] = gb + (size_t)(g0 + row) * K + slot * 8;
        lp[ii] = smem + pl * 4096 + seg * 512;
    }

    int rl = lane & 15, kb = lane >> 4;

    for (int k0 = 0; k0 < K; k0 += 32) {
        #pragma unroll
        for (int ii = 0; ii < NSEG; ii++) gload_lds16(gp[ii] + k0, lp[ii]);
        __syncthreads();

        bf16x8 afh[4], afl_[4], bfh[4], bfl[4];
        #pragma unroll
        for (int f = 0; f < 4; f++) {
            int r = wr * 64 + f * 16 + rl;
            int off = r * 32 + ((kb ^ ((r >> 1) & 3)) << 3);
            afh[f] = *(const bf16x8*)(smem + off);
            if (TERMS == 3) afl_[f] = *(const bf16x8*)(smem + pAl + off);
        }
        #pragma unroll
        for (int j = 0; j < 4; j++) {
            int r = wc * 64 + j * 16 + rl;
            int off = r * 32 + ((kb ^ ((r >> 1) & 3)) << 3);
            bfh[j] = *(const bf16x8*)(smem + pBh + off);
            bfl[j] = *(const bf16x8*)(smem + pBl + off);
        }
        #pragma unroll
        for (int i = 0; i < 4; i++)
            #pragma unroll
            for (int j = 0; j < 4; j++) {
                if (TERMS == 3)
                    acc[i][j] = __builtin_amdgcn_mfma_f32_16x16x32_bf16(
                        afl_[i], bfh[j], acc[i][j], 0, 0, 0);
                acc[i][j] = __builtin_amdgcn_mfma_f32_16x16x32_bf16(
                    afh[i], bfl[j], acc[i][j], 0, 0, 0);
                acc[i][j] = __builtin_amdgcn_mfma_f32_16x16x32_bf16(
                    afh[i], bfh[j], acc[i][j], 0, 0, 0);
            }
        __syncthreads();
    }

    int cr = kb * 4;
    #pragma unroll
    for (int i = 0; i < 4; i++) {
        #pragma unroll
        for (int j = 0; j < 4; j++) {
            int col = col0 + wc * 64 + j * 16 + rl;
            float bv = (MODE == 1) ? bias[col] : 0.f;
            f32x4 v = acc[i][j];
            #pragma unroll
            for (int q = 0; q < 4; q++) {
                float o = v[q] + bv;
                if (MODE == 1) o = o > 0.f ? o : __expf(o) - 1.f;
                size_t grow = (size_t)(row0 + wr * 64 + i * 16 + cr + q);
                C[grow * 512 + col] = o;
            }
        }
    }
}

// ------------------------------ attention ---------------------------------
__global__ __launch_bounds__(256) void alpha0_k(const float* __restrict__ h0,
                                                const float* __restrict__ att_s,
                                                const float* __restrict__ att_d,
                                                float* __restrict__ as_,
                                                float* __restrict__ ad_) {
    int n = blockIdx.x * 4 + (threadIdx.x >> 6);
    int l = threadIdx.x & 63;
    int h = l >> 3, i = l & 7;
    float ps = 0.f, pd = 0.f;
    #pragma unroll
    for (int c = 0; c < 64; c += 8) {
        float v = h0[(size_t)n * 512 + h * 64 + c + i];
        ps += v * att_s[h * 64 + c + i];
        pd += v * att_d[h * 64 + c + i];
    }
    #pragma unroll
    for (int off = 1; off < 8; off <<= 1) {
        ps += __shfl_xor(ps, off);
        pd += __shfl_xor(pd, off);
    }
    if (i == 0) {
        as_[n * 8 + h] = ps;
        ad_[n * 8 + h] = pd;
    }
}

__global__ __launch_bounds__(256) void prep1_k(const float* __restrict__ W1,
                                               const float* __restrict__ as1,
                                               const float* __restrict__ ad1,
                                               float* __restrict__ ws1,
                                               float* __restrict__ wd1) {
    int k = blockIdx.x;
    int t = threadIdx.x;
    int h = t >> 5, lane = t & 31;
    float ps = 0.f, pd = 0.f;
    for (int c = lane; c < 512; c += 32) {
        float w = W1[(size_t)k * 4096 + h * 512 + c];
        ps += w * as1[h * 512 + c];
        pd += w * ad1[h * 512 + c];
    }
    #pragma unroll
    for (int off = 1; off < 32; off <<= 1) {
        ps += __shfl_xor(ps, off);
        pd += __shfl_xor(pd, off);
    }
    if (lane == 0) {
        ws1[k * 8 + h] = ps;
        wd1[k * 8 + h] = pd;
    }
}

// ---------------------------------------------------------------------------
// node0w: ONE WAVE PER NODE (4 nodes/block, zero barriers). Lane l: softmax
// head h=l>>3 (stripe l&7); aggregates channels 8l..8l+7 (same head).
// ---------------------------------------------------------------------------
__global__ __launch_bounds__(256) void node0w_k(
    const float* __restrict__ h0, const float* __restrict__ asrc,
    const float* __restrict__ adst, const int* __restrict__ indptr,
    const int* __restrict__ csr, const float* __restrict__ b0,
    const float* __restrict__ ws1, const float* __restrict__ wd1,
    float* __restrict__ hl0, float* __restrict__ as1, float* __restrict__ ad1) {
    int b = blockIdx.x;
    int wid = threadIdx.x >> 6;
    int l = threadIdx.x & 63;
    int d = (b & 7) * (NNODES / 8) + ((b >> 3) << 2) + wid;  // XCD-pinned
    int h = l >> 3;
    int e0 = indptr[d];
    int ne = indptr[d + 1] - e0;   // real edges; e==ne is the self loop
    float adh = adst[d * 8 + h];

    float m = -3.0e38f, z = 0.f;
    for (int e = (l & 7); e <= ne; e += 8) {
        int s = (e < ne) ? csr[e0 + e] : d;
        float v = asrc[s * 8 + h] + adh;
        v = v > 0.f ? v : 0.2f * v;
        float mn = fmaxf(m, v);
        z = z * __expf(m - mn) + __expf(v - mn);
        m = mn;
    }
    #pragma unroll
    for (int off = 1; off < 8; off <<= 1) {
        float mo = __shfl_xor(m, off);
        float zo = __shfl_xor(z, off);
        float mn = fmaxf(m, mo);
        z = z * __expf(m - mn) + zo * __expf(mo - mn);
        m = mn;
    }
    float rz = 1.0f / (z + 1e-16f);

    float acc[8] = {};
    for (int eb = 0; eb <= ne; eb += 8) {
        int idx = eb + (l & 7);
        int sv = (idx < ne) ? csr[e0 + idx] : d;
        int nn = min(8, ne + 1 - eb);
        #pragma unroll
        for (int i = 0; i < 8; i++) {
            if (i < nn) {
                int s = __shfl(sv, (l & 56) | i);
                float v = asrc[s * 8 + h] + adh;
                v = v > 0.f ? v : 0.2f * v;
                float a = __expf(v - m) * rz;
                const float4* hp = (const float4*)(h0 + ((size_t)s << 9) + 8 * l);
                float4 v0 = hp[0], v1 = hp[1];
                acc[0] = fmaf(a, v0.x, acc[0]);
                acc[1] = fmaf(a, v0.y, acc[1]);
                acc[2] = fmaf(a, v0.z, acc[2]);
                acc[3] = fmaf(a, v0.w, acc[3]);
                acc[4] = fmaf(a, v1.x, acc[4]);
                acc[5] = fmaf(a, v1.y, acc[5]);
                acc[6] = fmaf(a, v1.z, acc[6]);
                acc[7] = fmaf(a, v1.w, acc[7]);
            }
        }
    }

    const float4* b4 = (const float4*)(b0 + 8 * l);
    float4 bva = b4[0], bvb = b4[1];
    float o[8];
    o[0] = acc[0] + bva.x; o[1] = acc[1] + bva.y;
    o[2] = acc[2] + bva.z; o[3] = acc[3] + bva.w;
    o[4] = acc[4] + bvb.x; o[5] = acc[5] + bvb.y;
    o[6] = acc[6] + bvb.z; o[7] = acc[7] + bvb.w;
    #pragma unroll
    for (int k = 0; k < 8; k++) o[k] = o[k] > 0.f ? o[k] : __expf(o[k]) - 1.f;
    float* hr = hl0 + ((size_t)d << 9) + 8 * l;
    *(float4*)hr = make_float4(o[0], o[1], o[2], o[3]);
    *(float4*)(hr + 4) = make_float4(o[4], o[5], o[6], o[7]);

    float ps[8] = {}, pd[8] = {};
    #pragma unroll
    for (int k = 0; k < 8; k++) {
        const float4* w4 = (const float4*)(ws1 + (size_t)(8 * l + k) * 8);
        const float4* v4 = (const float4*)(wd1 + (size_t)(8 * l + k) * 8);
        float4 wa = w4[0], wb = w4[1];
        float4 va = v4[0], vb = v4[1];
        float ok = o[k];
        ps[0] = fmaf(ok, wa.x, ps[0]); ps[1] = fmaf(ok, wa.y, ps[1]);
        ps[2] = fmaf(ok, wa.z, ps[2]); ps[3] = fmaf(ok, wa.w, ps[3]);
        ps[4] = fmaf(ok, wb.x, ps[4]); ps[5] = fmaf(ok, wb.y, ps[5]);
        ps[6] = fmaf(ok, wb.z, ps[6]); ps[7] = fmaf(ok, wb.w, ps[7]);
        pd[0] = fmaf(ok, va.x, pd[0]); pd[1] = fmaf(ok, va.y, pd[1]);
        pd[2] = fmaf(ok, va.z, pd[2]); pd[3] = fmaf(ok, va.w, pd[3]);
        pd[4] = fmaf(ok, vb.x, pd[4]); pd[5] = fmaf(ok, vb.y, pd[5]);
        pd[6] = fmaf(ok, vb.z, pd[6]); pd[7] = fmaf(ok, vb.w, pd[7]);
    }
    #pragma unroll
    for (int off = 1; off < 64; off <<= 1) {
        #pragma unroll
        for (int j = 0; j < 8; j++) {
            ps[j] += __shfl_xor(ps[j], off);
            pd[j] += __shfl_xor(pd[j], off);
        }
    }
    #pragma unroll
    for (int j = 0; j < 8; j++) {
        if (l == j) as1[(size_t)d * 8 + j] = ps[j];
        if (l == 8 + j) ad1[(size_t)d * 8 + j] = pd[j];
    }
}

// ---------------------------------------------------------------------------
// node1w: ONE WAVE PER NODE. Lane l: softmax head hme=l&7 (stripe l>>3);
// aggregates acc[8 heads][8 ch] for channels 8l..8l+7; per-edge alpha shared
// across the wave via 8 group-local shfls. Output bf16 single plane.
// ---------------------------------------------------------------------------
__global__ __launch_bounds__(256) void node1w_k(
    const float* __restrict__ hl0, const float* __restrict__ asrc,
    const float* __restrict__ adst, const int* __restrict__ indptr,
    const int* __restrict__ csr, u16* __restrict__ aggh, int base, int ch) {
    int b = blockIdx.x;
    int wid = threadIdx.x >> 6;
    int l = threadIdx.x & 63;
    int dl = (b & 7) * (ch >> 3) + ((b >> 3) << 2) + wid;
    int d = base + dl;
    int hme = l & 7;
    int e0 = indptr[d];
    int ne = indptr[d + 1] - e0;
    float adh = adst[d * 8 + hme];

    float m = -3.0e38f, z = 0.f;
    for (int e = (l >> 3); e <= ne; e += 8) {
        int s = (e < ne) ? csr[e0 + e] : d;
        float v = asrc[s * 8 + hme] + adh;
        v = v > 0.f ? v : 0.2f * v;
        float mn = fmaxf(m, v);
        z = z * __expf(m - mn) + __expf(v - mn);
        m = mn;
    }
    #pragma unroll
    for (int off = 8; off < 64; off <<= 1) {
        float mo = __shfl_xor(m, off);
        float zo = __shfl_xor(z, off);
        float mn = fmaxf(m, mo);
        z = z * __expf(m - mn) + zo * __expf(mo - mn);
        m = mn;
    }
    float rz = 1.0f / (z + 1e-16f);

    float acc[8][8] = {};
    for (int eb = 0; eb <= ne; eb += 8) {
        int idx = eb + (l & 7);
        int sv = (idx < ne) ? csr[e0 + idx] : d;
        int nn = min(8, ne + 1 - eb);
        #pragma unroll
        for (int i = 0; i < 8; i++) {
            if (i < nn) {
                int s = __shfl(sv, (l & 56) | i);
                float v = asrc[s * 8 + hme] + adh;
                v = v > 0.f ? v : 0.2f * v;
                float amine = __expf(v - m) * rz;
                float a[8];
                #pragma unroll
                for (int hh = 0; hh < 8; hh++)
                    a[hh] = __shfl(amine, (l & 56) | hh);
                const float4* hp = (const float4*)(hl0 + ((size_t)s << 9) + 8 * l);
                float4 v0 = hp[0], v1 = hp[1];
                #pragma unroll
                for (int hh = 0; hh < 8; hh++) {
                    acc[hh][0] = fmaf(a[hh], v0.x, acc[hh][0]);
                    acc[hh][1] = fmaf(a[hh], v0.y, acc[hh][1]);
                    acc[hh][2] = fmaf(a[hh], v0.z, acc[hh][2]);
                    acc[hh][3] = fmaf(a[hh], v0.w, acc[hh][3]);
                    acc[hh][4] = fmaf(a[hh], v1.x, acc[hh][4]);
                    acc[hh][5] = fmaf(a[hh], v1.y, acc[hh][5]);
                    acc[hh][6] = fmaf(a[hh], v1.z, acc[hh][6]);
                    acc[hh][7] = fmaf(a[hh], v1.w, acc[hh][7]);
                }
            }
        }
    }

    #pragma unroll
    for (int hh = 0; hh < 8; hh++) {
        ushort4 qa = make_ushort4(f2bf(acc[hh][0]), f2bf(acc[hh][1]),
                                  f2bf(acc[hh][2]), f2bf(acc[hh][3]));
        ushort4 qb = make_ushort4(f2bf(acc[hh][4]), f2bf(acc[hh][5]),
                                  f2bf(acc[hh][6]), f2bf(acc[hh][7]));
        size_t ob = (size_t)dl * 4096 + hh * 512 + 8 * l;
        *(ushort4*)(aggh + ob) = qa;
        *(ushort4*)(aggh + ob + 4) = qb;
    }
}

// ------------------------------- launcher ----------------------------------
extern "C" void kernel_launch(void* const* d_in, const int* in_sizes, int n_in,
                              void* d_out, int out_size, void* d_ws, size_t ws_size,
                              hipStream_t stream) {
    const float* x = (const float*)d_in[0];
    const int* ei = (const int*)d_in[1];
    const float* W0 = (const float*)d_in[2];
    const float* at_s0 = (const float*)d_in[3];
    const float* at_d0 = (const float*)d_in[4];
    const float* b0 = (const float*)d_in[5];
    const float* W1 = (const float*)d_in[6];
    const float* at_s1 = (const float*)d_in[7];
    const float* at_d1 = (const float*)d_in[8];
    const float* b1 = (const float*)d_in[9];
    float* out = (float*)d_out;

    const int N = NNODES;
    const int E = in_sizes[1] / 2;
    const int* esrc = ei;
    const int* edst = ei + E;

    char* p = (char*)d_ws;
    auto carve = [&](size_t bytes) -> void* {
        void* r = (void*)p;
        p += ((bytes + 255) & ~(size_t)255);
        return r;
    };
    float* h0 = (float*)carve((size_t)N * 512 * 4);
    float* hl0 = (float*)carve((size_t)N * 512 * 4);
    float* as0 = (float*)carve((size_t)N * 8 * 4);
    float* ad0 = (float*)carve((size_t)N * 8 * 4);
    float* as1 = (float*)carve((size_t)N * 8 * 4);
    float* ad1 = (float*)carve((size_t)N * 8 * 4);
    int* deg = (int*)carve((size_t)N * 4);
    int* indptr = (int*)carve((size_t)(N + 1) * 4);
    int* cursor = (int*)carve((size_t)N * 4);
    int* csr = (int*)carve((size_t)E * 4);
    float* ws1 = (float*)carve(512 * 8 * 4);
    float* wd1 = (float*)carve(512 * 8 * 4);
    u16* xh = (u16*)carve((size_t)N * 512 * 2);
    u16* xl = (u16*)carve((size_t)N * 512 * 2);
    u16* W0h = (u16*)carve((size_t)512 * 512 * 2);
    u16* W0l = (u16*)carve((size_t)512 * 512 * 2);
    u16* B1h = (u16*)carve((size_t)512 * 4096 * 2);
    u16* B1l = (u16*)carve((size_t)512 * 4096 * 2);
    size_t used = (size_t)(p - (char*)d_ws);

    int CH = 1024;
    const int cands[5] = {16384, 8192, 4096, 2048, 1024};
    for (int ci = 0; ci < 5; ci++) {
        if (ws_size >= used + (size_t)cands[ci] * 8192 + 512) {
            CH = cands[ci];
            break;
        }
    }
    u16* aggh = (u16*)carve((size_t)CH * 4096 * 2);

    // CSR build
    zero_k<<<(N + 255) / 256, 256, 0, stream>>>(deg, N);
    count_k<<<(E + 255) / 256, 256, 0, stream>>>(edst, E, deg);
    scan_k<<<1, 1024, 0, stream>>>(deg, indptr, cursor, N);
    scatter_k<<<(E + 255) / 256, 256, 0, stream>>>(esrc, edst, E, cursor, csr);

    // operand prep (split bf16) + folded layer-1 attention weights
    prepx_k<<<(N * 512 / 4 + 255) / 256, 256, 0, stream>>>(x, xh, xl);
    prepW0t_k<<<64, 256, 0, stream>>>(W0, W0h, W0l);
    prepW1t_k<<<512, 256, 0, stream>>>(W1, B1h, B1l);
    prep1_k<<<512, 256, 0, stream>>>(W1, at_s1, at_d1, ws1, wd1);

    // Layer 0
    mgemm_k<0, 3><<<dim3(4, N / 128), 256, 0, stream>>>(
        xh, xl, W0h, W0l, h0, 512, nullptr);
    alpha0_k<<<N / 4, 256, 0, stream>>>(h0, at_s0, at_d0, as0, ad0);
    node0w_k<<<N / 4, 256, 0, stream>>>(h0, as0, ad0, indptr, csr, b0, ws1, wd1,
                                        hl0, as1, ad1);

    // Layer 1: bf16 aggregate per chunk, 2-term fused GEMM (+b1, ELU)
    for (int base = 0; base < N; base += CH) {
        node1w_k<<<CH / 4, 256, 0, stream>>>(hl0, as1, ad1, indptr, csr, aggh,
                                             base, CH);
        mgemm_k<1, 2><<<dim3(4, CH / 128), 256, 0, stream>>>(
            aggh, nullptr, B1h, B1l, out + (size_t)base * 512, 4096, b1);
    }
}